// Round 1
// baseline (629.015 us; speedup 1.0000x reference)
//
#include <hip/hip_runtime.h>
#include <stdint.h>

// Problem constants: B=2, C=256, N=65536
#define NEDGE 65536

typedef __attribute__((ext_vector_type(4))) float f32x4;
typedef __attribute__((ext_vector_type(8))) __bf16 bf16x8;

__device__ __forceinline__ uint16_t f2bf(float f) {
  union { float f; uint32_t u; } v; v.f = f;
  uint32_t r = v.u + 0x7FFFu + ((v.u >> 16) & 1u);
  return (uint16_t)(r >> 16);
}
__device__ __forceinline__ float bflo(uint32_t u) {
  union { uint32_t u; float f; } v; v.u = u << 16; return v.f;
}
__device__ __forceinline__ float bfhi(uint32_t u) {
  union { uint32_t u; float f; } v; v.u = u & 0xFFFF0000u; return v.f;
}
__device__ __forceinline__ uint32_t packbf(float lo, float hi) {
  return (uint32_t)f2bf(lo) | ((uint32_t)f2bf(hi) << 16);
}
__device__ __forceinline__ void gload_lds16(const void* g, void* l) {
  __builtin_amdgcn_global_load_lds(
      (__attribute__((address_space(1))) uint32_t*)(uintptr_t)g,
      (__attribute__((address_space(3))) uint32_t*)l, 16, 0, 0);
}
__device__ __forceinline__ float sigm(float z) { return 1.0f / (1.0f + __expf(-z)); }

// ---------------- K0: weight composition ----------------
// Wt (512 rows j, 640 cols kk) bf16, row-major. Row j = output col of Y=[ya|yb].
// kk<128: XA (self) coeff = Wl^T Wf_local + Wtri[:,:,0]^T Wf_tri
// kk blocks of 128 after that map to g-features in order F1(g1),F3(g3),F2(g2),F4(g4).
__global__ void k_compose(const float* __restrict__ Wal, const float* __restrict__ Wbl,
                          const float* __restrict__ Wat, const float* __restrict__ Wbt,
                          const float* __restrict__ Waf, const float* __restrict__ Wbf,
                          uint16_t* __restrict__ Wt) {
  int id = blockIdx.x * 256 + threadIdx.x;
  if (id >= 512 * 640) return;
  int j = id / 640, kk = id % 640;
  const float* Wf = (j < 256) ? Waf : Wbf;
  const float* Wl = (j < 256) ? Wal : Wbl;
  const float* Wr = (j < 256) ? Wat : Wbt;
  int jj = j & 255;
  float acc = 0.f;
  if (kk < 128) {
    int c = kk;
    for (int o = 0; o < 128; ++o) acc += Wl[o * 128 + c] * Wf[jj * 256 + o];
    for (int o = 0; o < 128; ++o) acc += Wr[(o * 128 + c) * 5 + 0] * Wf[jj * 256 + 128 + o];
  } else {
    int blkid = (kk - 128) >> 7;
    int gk = (blkid == 0) ? 1 : (blkid == 1) ? 3 : (blkid == 2) ? 2 : 4;
    int c = (kk - 128) & 127;
    for (int o = 0; o < 128; ++o) acc += Wr[(o * 128 + c) * 5 + gk] * Wf[jj * 256 + 128 + o];
  }
  Wt[j * 640 + kk] = f2bf(acc);
}

__global__ void k_bias(const float* __restrict__ bal, const float* __restrict__ bat,
                       const float* __restrict__ baf, const float* __restrict__ bbl,
                       const float* __restrict__ bbt, const float* __restrict__ bbf,
                       const float* __restrict__ Waf, const float* __restrict__ Wbf,
                       float* __restrict__ biasF) {
  int id = blockIdx.x * 256 + threadIdx.x;
  if (id >= 512) return;
  const float* Wf = (id < 256) ? Waf : Wbf;
  const float* bl = (id < 256) ? bal : bbl;
  const float* bt = (id < 256) ? bat : bbt;
  const float* bsf = (id < 256) ? baf : bbf;
  int jj = id & 255;
  float acc = bsf[jj];
  for (int o = 0; o < 128; ++o) acc += Wf[jj * 256 + o] * bl[o];
  for (int o = 0; o < 128; ++o) acc += Wf[jj * 256 + 128 + o] * bt[o];
  biasF[id] = acc;
}

// First-layer weights transposed to c-major: Wt1[c][j] (256 x 128 f32)
__global__ void k_wt1(const float* __restrict__ Wa, const float* __restrict__ Wb,
                      float* __restrict__ Wt1) {
  int id = blockIdx.x * 256 + threadIdx.x;
  if (id >= 256 * 128) return;
  int c = id >> 7, j = id & 127;
  Wt1[c * 128 + j] = (j < 64) ? Wa[j * 256 + c] : Wb[(j - 64) * 256 + c];
}

// ---------------- K1: XA = [Wa@x0+ba | Wb@x1+bb], (B, N, 128) bf16 ----------------
__global__ __launch_bounds__(256, 2) void k1_xa(
    const float* __restrict__ x0, const float* __restrict__ x1,
    const float* __restrict__ Wt1, const float* __restrict__ ba,
    const float* __restrict__ bb, uint16_t* __restrict__ XA) {
  int blk = blockIdx.x;
  int b = blk >> 8;                 // 256 blocks per batch
  int n = ((blk & 255) << 8) + threadIdx.x;
  const float* xa = x0 + (size_t)b * 256 * NEDGE + n;
  const float* xb = x1 + (size_t)b * 256 * NEDGE + n;
  float accA[64];
  float accB[64];
#pragma unroll
  for (int j = 0; j < 64; ++j) { accA[j] = 0.f; accB[j] = 0.f; }
  for (int c = 0; c < 256; ++c) {
    float va = xa[(size_t)c * NEDGE];
    float vb = xb[(size_t)c * NEDGE];
    const float* wr = Wt1 + c * 128;
#pragma unroll
    for (int j = 0; j < 64; ++j) accA[j] += va * wr[j];
#pragma unroll
    for (int j = 0; j < 64; ++j) accB[j] += vb * wr[64 + j];
  }
  uint4* dst = (uint4*)(XA + ((size_t)b * NEDGE + n) * 128);
#pragma unroll
  for (int i = 0; i < 8; ++i) {
    uint4 v;
    v.x = packbf(accA[8*i+0] + ba[8*i+0], accA[8*i+1] + ba[8*i+1]);
    v.y = packbf(accA[8*i+2] + ba[8*i+2], accA[8*i+3] + ba[8*i+3]);
    v.z = packbf(accA[8*i+4] + ba[8*i+4], accA[8*i+5] + ba[8*i+5]);
    v.w = packbf(accA[8*i+6] + ba[8*i+6], accA[8*i+7] + ba[8*i+7]);
    dst[i] = v;
  }
#pragma unroll
  for (int i = 0; i < 8; ++i) {
    uint4 v;
    v.x = packbf(accB[8*i+0] + bb[8*i+0], accB[8*i+1] + bb[8*i+1]);
    v.y = packbf(accB[8*i+2] + bb[8*i+2], accB[8*i+3] + bb[8*i+3]);
    v.z = packbf(accB[8*i+4] + bb[8*i+4], accB[8*i+5] + bb[8*i+5]);
    v.w = packbf(accB[8*i+6] + bb[8*i+6], accB[8*i+7] + bb[8*i+7]);
    dst[8 + i] = v;
  }
}

// ---------------- K2: gather + symmetric features -> G (N, 512) bf16 ----------------
// G cols: [0,128)=f1+f3, [128,256)=|f1-f3|, [256,384)=f2+f4, [384,512)=|f2-f4|
__device__ __forceinline__ void feat_pair(uint32_t u1, uint32_t u3, uint32_t& s, uint32_t& d) {
  float a1 = bflo(u1), b1 = bfhi(u1), a3 = bflo(u3), b3 = bfhi(u3);
  s = packbf(a1 + a3, b1 + b3);
  d = packbf(fabsf(a1 - a3), fabsf(b1 - b3));
}
__global__ void k2_gather(const uint16_t* __restrict__ XAb, const int* __restrict__ gidx,
                          uint16_t* __restrict__ G) {
  int t = threadIdx.x;
  int wid = t >> 6, lane = t & 63;
  int wbase = (blockIdx.x * 4 + wid) * 16;
  int g = lane >> 4, sl = lane & 15;
  for (int it = 0; it < 4; ++it) {
    int e0 = wbase + it * 4;
    int myidx = 0;
    if (lane < 16) myidx = gidx[(size_t)e0 * 4 + lane];
    int e = e0 + g;
    int i1 = __shfl(myidx, g * 4 + 0);
    int i2 = __shfl(myidx, g * 4 + 1);
    int i3 = __shfl(myidx, g * 4 + 2);
    int i4 = __shfl(myidx, g * 4 + 3);
    uint4 v1 = ((const uint4*)(XAb + (size_t)i1 * 128))[sl];
    uint4 v2 = ((const uint4*)(XAb + (size_t)i2 * 128))[sl];
    uint4 v3 = ((const uint4*)(XAb + (size_t)i3 * 128))[sl];
    uint4 v4 = ((const uint4*)(XAb + (size_t)i4 * 128))[sl];
    uint4 F1, F3, F2, F4;
    feat_pair(v1.x, v3.x, F1.x, F3.x); feat_pair(v1.y, v3.y, F1.y, F3.y);
    feat_pair(v1.z, v3.z, F1.z, F3.z); feat_pair(v1.w, v3.w, F1.w, F3.w);
    feat_pair(v2.x, v4.x, F2.x, F4.x); feat_pair(v2.y, v4.y, F2.y, F4.y);
    feat_pair(v2.z, v4.z, F2.z, F4.z); feat_pair(v2.w, v4.w, F2.w, F4.w);
    uint4* outr = (uint4*)(G + (size_t)e * 512);
    outr[sl] = F1; outr[16 + sl] = F3; outr[32 + sl] = F2; outr[48 + sl] = F4;
  }
}

// ---------------- K3: Y (N,512) = [XA|G](N,640) @ Wt^T + bias, bf16 out ----------------
__global__ __launch_bounds__(256, 2) void k3_gemm(
    const uint16_t* __restrict__ XAb, const uint16_t* __restrict__ G,
    const uint16_t* __restrict__ Wt, const float* __restrict__ biasF,
    uint16_t* __restrict__ Y) {
  __shared__ __align__(16) uint16_t As[128 * 64];
  __shared__ __align__(16) uint16_t Bs[128 * 64];
  int bx = blockIdx.y;   // 0..511 row tile (y so that consecutive blocks share A-tile)
  int by = blockIdx.x;   // 0..3 col tile
  int t = threadIdx.x;
  int ebase = bx * 128;
  int jbase = by * 128;
  int wid = t >> 6, lane = t & 63;
  int wr = wid >> 1, wc = wid & 1;
  int m = lane & 15, half = lane >> 4;

  f32x4 acc[4][4];
  f32x4 zero = {0.f, 0.f, 0.f, 0.f};
#pragma unroll
  for (int r = 0; r < 4; ++r)
#pragma unroll
    for (int c = 0; c < 4; ++c) acc[r][c] = zero;

  for (int s = 0; s < 10; ++s) {
    const uint16_t* srcbase; size_t rstride; int koff;
    if (s < 2) { srcbase = XAb; rstride = 128; koff = s * 64; }
    else       { srcbase = G;   rstride = 512; koff = (s - 2) * 64; }
#pragma unroll
    for (int i = 0; i < 4; ++i) {
      int slot = i * 256 + t;
      int r = slot >> 3, c16 = slot & 7;
      gload_lds16(srcbase + (size_t)(ebase + r) * rstride + koff + c16 * 8, &As[slot * 8]);
    }
#pragma unroll
    for (int i = 0; i < 4; ++i) {
      int slot = i * 256 + t;
      int r = slot >> 3, c16 = slot & 7;
      gload_lds16(Wt + (size_t)(jbase + r) * 640 + s * 64 + c16 * 8, &Bs[slot * 8]);
    }
    asm volatile("s_waitcnt vmcnt(0)" ::: "memory");
    __syncthreads();
#pragma unroll
    for (int kit = 0; kit < 2; ++kit) {
      bf16x8 af[4], bf[4];
#pragma unroll
      for (int r = 0; r < 4; ++r) {
        int row = wr * 64 + r * 16 + m;
        af[r] = *(const bf16x8*)&As[row * 64 + kit * 32 + half * 8];
      }
#pragma unroll
      for (int cf = 0; cf < 4; ++cf) {
        int row = wc * 64 + cf * 16 + m;
        bf[cf] = *(const bf16x8*)&Bs[row * 64 + kit * 32 + half * 8];
      }
#pragma unroll
      for (int r = 0; r < 4; ++r)
#pragma unroll
        for (int cf = 0; cf < 4; ++cf)
          acc[r][cf] = __builtin_amdgcn_mfma_f32_16x16x32_bf16(af[r], bf[cf], acc[r][cf], 0, 0, 0);
    }
    __syncthreads();
  }
  // epilogue: C/D layout col=lane&15, row=(lane>>4)*4+q
#pragma unroll
  for (int cf = 0; cf < 4; ++cf) {
    int col = jbase + wc * 64 + cf * 16 + m;
    float bv = biasF[col];
#pragma unroll
    for (int r = 0; r < 4; ++r) {
      int rowb = ebase + wr * 64 + r * 16 + half * 4;
#pragma unroll
      for (int q = 0; q < 4; ++q) {
        float v = acc[r][cf][q] + bv;
        Y[(size_t)(rowb + q) * 512 + col] = f2bf(v);
      }
    }
  }
}

// ---------------- K3b: per-column stats (deterministic two-stage) ----------------
__global__ void k3b1(const uint16_t* __restrict__ Y, float* __restrict__ part) {
  int t = threadIdx.x, ch = blockIdx.x;  // 512 chunks of 128 rows
  const uint32_t* Y32 = (const uint32_t*)Y;
  float s1a = 0, s2a = 0, s1b = 0, s2b = 0;
  size_t base = (size_t)ch * 128 * 256 + t;
  for (int r = 0; r < 128; ++r) {
    uint32_t v = Y32[base + (size_t)r * 256];
    float x = bflo(v), y = bfhi(v);
    s1a += x; s2a += x * x; s1b += y; s2b += y * y;
  }
  float* p = part + ((size_t)ch * 512 + 2 * t) * 2;
  p[0] = s1a; p[1] = s2a; p[2] = s1b; p[3] = s2b;
}
__global__ void k3b2(const float* __restrict__ part, float* __restrict__ statF) {
  int col = blockIdx.x, t = threadIdx.x;  // 128 threads
  float s1 = 0, s2 = 0;
  for (int k = t; k < 512; k += 128) {
    const float* p = part + ((size_t)k * 512 + col) * 2;
    s1 += p[0]; s2 += p[1];
  }
  for (int off = 32; off; off >>= 1) { s1 += __shfl_down(s1, off); s2 += __shfl_down(s2, off); }
  __shared__ float sh[4];
  if ((t & 63) == 0) { sh[(t >> 6) * 2] = s1; sh[(t >> 6) * 2 + 1] = s2; }
  __syncthreads();
  if (t == 0) {
    s1 = sh[0] + sh[2]; s2 = sh[1] + sh[3];
    float mean = s1 * (1.0f / 65536.0f);
    float var = s2 * (1.0f / 65536.0f) - mean * mean;
    statF[col * 2] = mean;
    statF[col * 2 + 1] = rsqrtf(var + 1e-5f);
  }
}

// ---------------- K4: gate + blend, channel-major out ----------------
__global__ __launch_bounds__(256) void k4_final(
    const uint16_t* __restrict__ Y, const float* __restrict__ statF,
    const float* __restrict__ x0b, const float* __restrict__ x1b,
    float* __restrict__ outb) {
  __shared__ float W0[128][65];
  __shared__ float mA[128], rA[128], mB[128], rB[128];
  int t = threadIdx.x;
  int n0 = blockIdx.x * 64;
  int ch = blockIdx.y;  // channel half
  if (t < 128) {
    mA[t] = statF[(ch * 128 + t) * 2];
    rA[t] = statF[(ch * 128 + t) * 2 + 1];
  } else {
    int q = t - 128;
    mB[q] = statF[(256 + ch * 128 + q) * 2];
    rB[q] = statF[(256 + ch * 128 + q) * 2 + 1];
  }
  __syncthreads();
  const char* Ybase = (const char*)Y;
  for (int i = t; i < 64 * 64; i += 256) {
    int row = i >> 6, cp = i & 63;
    const char* yr = Ybase + (size_t)(n0 + row) * 1024;
    uint32_t ya2 = *(const uint32_t*)(yr + ch * 256 + cp * 4);
    uint32_t yb2 = *(const uint32_t*)(yr + 512 + ch * 256 + cp * 4);
    int c0 = 2 * cp, c1 = 2 * cp + 1;
    float wa0 = sigm((bflo(ya2) - mA[c0]) * rA[c0]);
    float wa1 = sigm((bfhi(ya2) - mA[c1]) * rA[c1]);
    float wb0 = sigm((bflo(yb2) - mB[c0]) * rB[c0]);
    float wb1 = sigm((bfhi(yb2) - mB[c1]) * rB[c1]);
    W0[c0][row] = sigm(wa0 - wb0);
    W0[c1][row] = sigm(wa1 - wb1);
  }
  __syncthreads();
  int nn = t & 63, cg = t >> 6;
  for (int cc = cg; cc < 128; cc += 4) {
    int c = ch * 128 + cc;
    size_t gi = (size_t)c * NEDGE + n0 + nn;
    float w0 = W0[cc][nn];
    outb[gi] = x0b[gi] * w0 + x1b[gi] * (1.0f - w0);
  }
}

extern "C" void kernel_launch(void* const* d_in, const int* in_sizes, int n_in,
                              void* d_out, int out_size, void* d_ws, size_t ws_size,
                              hipStream_t stream) {
  const float* x0 = (const float*)d_in[0];
  const float* x1 = (const float*)d_in[1];
  const int* gemm = (const int*)d_in[2];
  const float* Wa = (const float*)d_in[3];
  const float* ba = (const float*)d_in[4];
  const float* Wb = (const float*)d_in[5];
  const float* bb = (const float*)d_in[6];
  const float* Wal = (const float*)d_in[7];
  const float* bal = (const float*)d_in[8];
  const float* Wbl = (const float*)d_in[9];
  const float* bbl = (const float*)d_in[10];
  const float* Wat = (const float*)d_in[11];
  const float* bat = (const float*)d_in[12];
  const float* Wbt = (const float*)d_in[13];
  const float* bbt = (const float*)d_in[14];
  const float* Waf = (const float*)d_in[15];
  const float* baf = (const float*)d_in[16];
  const float* Wbf = (const float*)d_in[17];
  const float* bbf = (const float*)d_in[18];
  float* out = (float*)d_out;

  char* ws = (char*)d_ws;
  uint16_t* XA   = (uint16_t*)ws;                    // 33,554,432 B
  uint16_t* G    = (uint16_t*)(ws + 33554432);       // 67,108,864 B (per-batch reuse)
  uint16_t* Yb   = (uint16_t*)(ws + 100663296);      // 67,108,864 B (per-batch reuse)
  uint16_t* Wt   = (uint16_t*)(ws + 167772160);      // 655,360 B
  float*    Wt1  = (float*)(ws + 168427520);         // 131,072 B
  float*    biasF= (float*)(ws + 168558592);         // 2,048 B
  float*    part = (float*)(ws + 168560640);         // 2,097,152 B
  float*    statF= (float*)(ws + 170657792);         // 8,192 B
  // total ~170.7 MB of d_ws

  k_compose<<<dim3(1280), dim3(256), 0, stream>>>(Wal, Wbl, Wat, Wbt, Waf, Wbf, Wt);
  k_bias<<<dim3(2), dim3(256), 0, stream>>>(bal, bat, baf, bbl, bbt, bbf, Waf, Wbf, biasF);
  k_wt1<<<dim3(128), dim3(256), 0, stream>>>(Wa, Wb, Wt1);
  k1_xa<<<dim3(512), dim3(256), 0, stream>>>(x0, x1, Wt1, ba, bb, XA);

  for (int b = 0; b < 2; ++b) {
    const uint16_t* XAb = XA + (size_t)b * NEDGE * 128;
    k2_gather<<<dim3(1024), dim3(256), 0, stream>>>(XAb, gemm + (size_t)b * NEDGE * 4, G);
    k3_gemm<<<dim3(4, 512), dim3(256), 0, stream>>>(XAb, G, Wt, biasF, Yb);
    k3b1<<<dim3(512), dim3(256), 0, stream>>>(Yb, part);
    k3b2<<<dim3(512), dim3(128), 0, stream>>>(part, statF + b * 1024);
    k4_final<<<dim3(1024, 2), dim3(256), 0, stream>>>(
        Yb, statF + b * 1024, x0 + (size_t)b * 256 * NEDGE,
        x1 + (size_t)b * 256 * NEDGE, out + (size_t)b * 256 * NEDGE);
  }
}

// Round 2
// 607.369 us; speedup vs baseline: 1.0356x; 1.0356x over previous
//
#include <hip/hip_runtime.h>
#include <stdint.h>

// Problem constants: B=2, C=256, N=65536
#define NEDGE 65536

typedef __attribute__((ext_vector_type(4))) float f32x4;
typedef __attribute__((ext_vector_type(8))) __bf16 bf16x8;

__device__ __forceinline__ uint16_t f2bf(float f) {
  union { float f; uint32_t u; } v; v.f = f;
  uint32_t r = v.u + 0x7FFFu + ((v.u >> 16) & 1u);
  return (uint16_t)(r >> 16);
}
__device__ __forceinline__ float bflo(uint32_t u) {
  union { uint32_t u; float f; } v; v.u = u << 16; return v.f;
}
__device__ __forceinline__ float bfhi(uint32_t u) {
  union { uint32_t u; float f; } v; v.u = u & 0xFFFF0000u; return v.f;
}
__device__ __forceinline__ uint32_t packbf(float lo, float hi) {
  return (uint32_t)f2bf(lo) | ((uint32_t)f2bf(hi) << 16);
}
__device__ __forceinline__ void gload_lds16(const void* g, void* l) {
  __builtin_amdgcn_global_load_lds(
      (__attribute__((address_space(1))) uint32_t*)(uintptr_t)g,
      (__attribute__((address_space(3))) uint32_t*)l, 16, 0, 0);
}
__device__ __forceinline__ float sigm(float z) { return 1.0f / (1.0f + __expf(-z)); }

// ---------------- K0: weight composition ----------------
__global__ void k_compose(const float* __restrict__ Wal, const float* __restrict__ Wbl,
                          const float* __restrict__ Wat, const float* __restrict__ Wbt,
                          const float* __restrict__ Waf, const float* __restrict__ Wbf,
                          uint16_t* __restrict__ Wt) {
  int id = blockIdx.x * 256 + threadIdx.x;
  if (id >= 512 * 640) return;
  int j = id / 640, kk = id % 640;
  const float* Wf = (j < 256) ? Waf : Wbf;
  const float* Wl = (j < 256) ? Wal : Wbl;
  const float* Wr = (j < 256) ? Wat : Wbt;
  int jj = j & 255;
  float acc = 0.f;
  if (kk < 128) {
    int c = kk;
    for (int o = 0; o < 128; ++o) acc += Wl[o * 128 + c] * Wf[jj * 256 + o];
    for (int o = 0; o < 128; ++o) acc += Wr[(o * 128 + c) * 5 + 0] * Wf[jj * 256 + 128 + o];
  } else {
    int blkid = (kk - 128) >> 7;
    int gk = (blkid == 0) ? 1 : (blkid == 1) ? 3 : (blkid == 2) ? 2 : 4;
    int c = (kk - 128) & 127;
    for (int o = 0; o < 128; ++o) acc += Wr[(o * 128 + c) * 5 + gk] * Wf[jj * 256 + 128 + o];
  }
  Wt[j * 640 + kk] = f2bf(acc);
}

__global__ void k_bias(const float* __restrict__ bal, const float* __restrict__ bat,
                       const float* __restrict__ baf, const float* __restrict__ bbl,
                       const float* __restrict__ bbt, const float* __restrict__ bbf,
                       const float* __restrict__ Waf, const float* __restrict__ Wbf,
                       float* __restrict__ biasF) {
  int id = blockIdx.x * 256 + threadIdx.x;
  if (id >= 512) return;
  const float* Wf = (id < 256) ? Waf : Wbf;
  const float* bl = (id < 256) ? bal : bbl;
  const float* bt = (id < 256) ? bat : bbt;
  const float* bsf = (id < 256) ? baf : bbf;
  int jj = id & 255;
  float acc = bsf[jj];
  for (int o = 0; o < 128; ++o) acc += Wf[jj * 256 + o] * bl[o];
  for (int o = 0; o < 128; ++o) acc += Wf[jj * 256 + 128 + o] * bt[o];
  biasF[id] = acc;
}

// First-layer weights transposed to c-major: Wt1[c][j] (256 x 128 f32)
__global__ void k_wt1(const float* __restrict__ Wa, const float* __restrict__ Wb,
                      float* __restrict__ Wt1) {
  int id = blockIdx.x * 256 + threadIdx.x;
  if (id >= 256 * 128) return;
  int c = id >> 7, j = id & 127;
  Wt1[c * 128 + j] = (j < 64) ? Wa[j * 256 + c] : Wb[(j - 64) * 256 + c];
}

// ---------------- K1: XA = [Wa@x0+ba | Wb@x1+bb], (B, N, 128) bf16 ----------------
// grid (256 n-blocks, 2 sides, 2 batches); each thread: 64 outputs of one side.
// c unrolled by 8 for MLP; weights read wave-uniform (scalar loads).
__global__ __launch_bounds__(256) void k1_xa(
    const float* __restrict__ x0, const float* __restrict__ x1,
    const float* __restrict__ Wt1, const float* __restrict__ ba,
    const float* __restrict__ bb, uint16_t* __restrict__ XA) {
  int nb = blockIdx.x;
  int side = blockIdx.y;
  int b = blockIdx.z;
  int n = nb * 256 + threadIdx.x;
  const float* xin = (side ? x1 : x0) + (size_t)b * 256 * NEDGE + n;
  const float* bias = side ? bb : ba;
  float acc[64];
#pragma unroll
  for (int j = 0; j < 64; ++j) acc[j] = 0.f;
  const float* W = Wt1 + side * 64;
  for (int c = 0; c < 256; c += 8) {
    float v[8];
#pragma unroll
    for (int u = 0; u < 8; ++u) v[u] = xin[(size_t)(c + u) * NEDGE];
#pragma unroll
    for (int u = 0; u < 8; ++u) {
      const float* wr = W + (size_t)(c + u) * 128;
#pragma unroll
      for (int j = 0; j < 64; ++j) acc[j] += v[u] * wr[j];
    }
  }
  uint4* dst = (uint4*)(XA + ((size_t)b * NEDGE + n) * 128 + side * 64);
#pragma unroll
  for (int i = 0; i < 8; ++i) {
    uint4 o;
    o.x = packbf(acc[8*i+0] + bias[8*i+0], acc[8*i+1] + bias[8*i+1]);
    o.y = packbf(acc[8*i+2] + bias[8*i+2], acc[8*i+3] + bias[8*i+3]);
    o.z = packbf(acc[8*i+4] + bias[8*i+4], acc[8*i+5] + bias[8*i+5]);
    o.w = packbf(acc[8*i+6] + bias[8*i+6], acc[8*i+7] + bias[8*i+7]);
    dst[i] = o;
  }
}

// ---------------- K2: gather + symmetric features -> G (N, 512) bf16 ----------------
// G cols: [0,128)=f1+f3, [128,256)=|f1-f3|, [256,384)=f2+f4, [384,512)=|f2-f4|
__device__ __forceinline__ void feat_pair(uint32_t u1, uint32_t u3, uint32_t& s, uint32_t& d) {
  float a1 = bflo(u1), b1 = bfhi(u1), a3 = bflo(u3), b3 = bfhi(u3);
  s = packbf(a1 + a3, b1 + b3);
  d = packbf(fabsf(a1 - a3), fabsf(b1 - b3));
}
__global__ void k2_gather(const uint16_t* __restrict__ XAb, const int* __restrict__ gidx,
                          uint16_t* __restrict__ G) {
  int t = threadIdx.x;
  int wid = t >> 6, lane = t & 63;
  int wbase = (blockIdx.x * 4 + wid) * 16;
  int g = lane >> 4, sl = lane & 15;
  for (int it = 0; it < 4; ++it) {
    int e0 = wbase + it * 4;
    int myidx = 0;
    if (lane < 16) myidx = gidx[(size_t)e0 * 4 + lane];
    int e = e0 + g;
    int i1 = __shfl(myidx, g * 4 + 0);
    int i2 = __shfl(myidx, g * 4 + 1);
    int i3 = __shfl(myidx, g * 4 + 2);
    int i4 = __shfl(myidx, g * 4 + 3);
    uint4 v1 = ((const uint4*)(XAb + (size_t)i1 * 128))[sl];
    uint4 v2 = ((const uint4*)(XAb + (size_t)i2 * 128))[sl];
    uint4 v3 = ((const uint4*)(XAb + (size_t)i3 * 128))[sl];
    uint4 v4 = ((const uint4*)(XAb + (size_t)i4 * 128))[sl];
    uint4 F1, F3, F2, F4;
    feat_pair(v1.x, v3.x, F1.x, F3.x); feat_pair(v1.y, v3.y, F1.y, F3.y);
    feat_pair(v1.z, v3.z, F1.z, F3.z); feat_pair(v1.w, v3.w, F1.w, F3.w);
    feat_pair(v2.x, v4.x, F2.x, F4.x); feat_pair(v2.y, v4.y, F2.y, F4.y);
    feat_pair(v2.z, v4.z, F2.z, F4.z); feat_pair(v2.w, v4.w, F2.w, F4.w);
    uint4* outr = (uint4*)(G + (size_t)e * 512);
    outr[sl] = F1; outr[16 + sl] = F3; outr[32 + sl] = F2; outr[48 + sl] = F4;
  }
}

// ---------------- K3: Y (N,512) = [XA|G](N,640) @ Wt^T + bias, bf16 out ----------------
__global__ __launch_bounds__(256, 2) void k3_gemm(
    const uint16_t* __restrict__ XAb, const uint16_t* __restrict__ G,
    const uint16_t* __restrict__ Wt, const float* __restrict__ biasF,
    uint16_t* __restrict__ Y) {
  __shared__ __align__(16) uint16_t As[128 * 64];
  __shared__ __align__(16) uint16_t Bs[128 * 64];
  int bx = blockIdx.y;   // 0..511 row tile
  int by = blockIdx.x;   // 0..3 col tile
  int t = threadIdx.x;
  int ebase = bx * 128;
  int jbase = by * 128;
  int wid = t >> 6, lane = t & 63;
  int wr = wid >> 1, wc = wid & 1;
  int m = lane & 15, half = lane >> 4;

  f32x4 acc[4][4];
  f32x4 zero = {0.f, 0.f, 0.f, 0.f};
#pragma unroll
  for (int r = 0; r < 4; ++r)
#pragma unroll
    for (int c = 0; c < 4; ++c) acc[r][c] = zero;

  for (int s = 0; s < 10; ++s) {
    const uint16_t* srcbase; size_t rstride; int koff;
    if (s < 2) { srcbase = XAb; rstride = 128; koff = s * 64; }
    else       { srcbase = G;   rstride = 512; koff = (s - 2) * 64; }
#pragma unroll
    for (int i = 0; i < 4; ++i) {
      int slot = i * 256 + t;
      int r = slot >> 3, c16 = slot & 7;
      gload_lds16(srcbase + (size_t)(ebase + r) * rstride + koff + c16 * 8, &As[slot * 8]);
    }
#pragma unroll
    for (int i = 0; i < 4; ++i) {
      int slot = i * 256 + t;
      int r = slot >> 3, c16 = slot & 7;
      gload_lds16(Wt + (size_t)(jbase + r) * 640 + s * 64 + c16 * 8, &Bs[slot * 8]);
    }
    asm volatile("s_waitcnt vmcnt(0)" ::: "memory");
    __syncthreads();
#pragma unroll
    for (int kit = 0; kit < 2; ++kit) {
      bf16x8 af[4], bf[4];
#pragma unroll
      for (int r = 0; r < 4; ++r) {
        int row = wr * 64 + r * 16 + m;
        af[r] = *(const bf16x8*)&As[row * 64 + kit * 32 + half * 8];
      }
#pragma unroll
      for (int cf = 0; cf < 4; ++cf) {
        int row = wc * 64 + cf * 16 + m;
        bf[cf] = *(const bf16x8*)&Bs[row * 64 + kit * 32 + half * 8];
      }
#pragma unroll
      for (int r = 0; r < 4; ++r)
#pragma unroll
        for (int cf = 0; cf < 4; ++cf)
          acc[r][cf] = __builtin_amdgcn_mfma_f32_16x16x32_bf16(af[r], bf[cf], acc[r][cf], 0, 0, 0);
    }
    __syncthreads();
  }
#pragma unroll
  for (int cf = 0; cf < 4; ++cf) {
    int col = jbase + wc * 64 + cf * 16 + m;
    float bv = biasF[col];
#pragma unroll
    for (int r = 0; r < 4; ++r) {
      int rowb = ebase + wr * 64 + r * 16 + half * 4;
#pragma unroll
      for (int q = 0; q < 4; ++q) {
        float v = acc[r][cf][q] + bv;
        Y[(size_t)(rowb + q) * 512 + col] = f2bf(v);
      }
    }
  }
}

// ---------------- K3b: per-column stats (deterministic two-stage) ----------------
__global__ void k3b1(const uint16_t* __restrict__ Y, float* __restrict__ part) {
  int t = threadIdx.x, ch = blockIdx.x;
  const uint32_t* Y32 = (const uint32_t*)Y;
  float s1a = 0, s2a = 0, s1b = 0, s2b = 0;
  size_t base = (size_t)ch * 128 * 256 + t;
  for (int r = 0; r < 128; ++r) {
    uint32_t v = Y32[base + (size_t)r * 256];
    float x = bflo(v), y = bfhi(v);
    s1a += x; s2a += x * x; s1b += y; s2b += y * y;
  }
  float* p = part + ((size_t)ch * 512 + 2 * t) * 2;
  p[0] = s1a; p[1] = s2a; p[2] = s1b; p[3] = s2b;
}
__global__ void k3b2(const float* __restrict__ part, float* __restrict__ statF) {
  int col = blockIdx.x, t = threadIdx.x;
  float s1 = 0, s2 = 0;
  for (int k = t; k < 512; k += 128) {
    const float* p = part + ((size_t)k * 512 + col) * 2;
    s1 += p[0]; s2 += p[1];
  }
  for (int off = 32; off; off >>= 1) { s1 += __shfl_down(s1, off); s2 += __shfl_down(s2, off); }
  __shared__ float sh[4];
  if ((t & 63) == 0) { sh[(t >> 6) * 2] = s1; sh[(t >> 6) * 2 + 1] = s2; }
  __syncthreads();
  if (t == 0) {
    s1 = sh[0] + sh[2]; s2 = sh[1] + sh[3];
    float mean = s1 * (1.0f / 65536.0f);
    float var = s2 * (1.0f / 65536.0f) - mean * mean;
    statF[col * 2] = mean;
    statF[col * 2 + 1] = rsqrtf(var + 1e-5f);
  }
}

// ---------------- K4: gate + blend, channel-major out ----------------
__global__ __launch_bounds__(256) void k4_final(
    const uint16_t* __restrict__ Y, const float* __restrict__ statF,
    const float* __restrict__ x0b, const float* __restrict__ x1b,
    float* __restrict__ outb) {
  __shared__ float W0[128][65];
  __shared__ float mA[128], rA[128], mB[128], rB[128];
  int t = threadIdx.x;
  int n0 = blockIdx.x * 64;
  int ch = blockIdx.y;
  if (t < 128) {
    mA[t] = statF[(ch * 128 + t) * 2];
    rA[t] = statF[(ch * 128 + t) * 2 + 1];
  } else {
    int q = t - 128;
    mB[q] = statF[(256 + ch * 128 + q) * 2];
    rB[q] = statF[(256 + ch * 128 + q) * 2 + 1];
  }
  __syncthreads();
  const char* Ybase = (const char*)Y;
  for (int i = t; i < 64 * 64; i += 256) {
    int row = i >> 6, cp = i & 63;
    const char* yr = Ybase + (size_t)(n0 + row) * 1024;
    uint32_t ya2 = *(const uint32_t*)(yr + ch * 256 + cp * 4);
    uint32_t yb2 = *(const uint32_t*)(yr + 512 + ch * 256 + cp * 4);
    int c0 = 2 * cp, c1 = 2 * cp + 1;
    float wa0 = sigm((bflo(ya2) - mA[c0]) * rA[c0]);
    float wa1 = sigm((bfhi(ya2) - mA[c1]) * rA[c1]);
    float wb0 = sigm((bflo(yb2) - mB[c0]) * rB[c0]);
    float wb1 = sigm((bfhi(yb2) - mB[c1]) * rB[c1]);
    W0[c0][row] = sigm(wa0 - wb0);
    W0[c1][row] = sigm(wa1 - wb1);
  }
  __syncthreads();
  int nn = t & 63, cg = t >> 6;
  for (int cc = cg; cc < 128; cc += 4) {
    int c = ch * 128 + cc;
    size_t gi = (size_t)c * NEDGE + n0 + nn;
    float w0 = W0[cc][nn];
    outb[gi] = x0b[gi] * w0 + x1b[gi] * (1.0f - w0);
  }
}

extern "C" void kernel_launch(void* const* d_in, const int* in_sizes, int n_in,
                              void* d_out, int out_size, void* d_ws, size_t ws_size,
                              hipStream_t stream) {
  const float* x0 = (const float*)d_in[0];
  const float* x1 = (const float*)d_in[1];
  const int* gemm = (const int*)d_in[2];
  const float* Wa = (const float*)d_in[3];
  const float* ba = (const float*)d_in[4];
  const float* Wb = (const float*)d_in[5];
  const float* bb = (const float*)d_in[6];
  const float* Wal = (const float*)d_in[7];
  const float* bal = (const float*)d_in[8];
  const float* Wbl = (const float*)d_in[9];
  const float* bbl = (const float*)d_in[10];
  const float* Wat = (const float*)d_in[11];
  const float* bat = (const float*)d_in[12];
  const float* Wbt = (const float*)d_in[13];
  const float* bbt = (const float*)d_in[14];
  const float* Waf = (const float*)d_in[15];
  const float* baf = (const float*)d_in[16];
  const float* Wbf = (const float*)d_in[17];
  const float* bbf = (const float*)d_in[18];
  float* out = (float*)d_out;

  char* ws = (char*)d_ws;
  uint16_t* XA   = (uint16_t*)ws;                    // 33,554,432 B
  uint16_t* G    = (uint16_t*)(ws + 33554432);       // 67,108,864 B (per-batch reuse)
  uint16_t* Yb   = (uint16_t*)(ws + 100663296);      // 67,108,864 B (per-batch reuse)
  uint16_t* Wt   = (uint16_t*)(ws + 167772160);      // 655,360 B
  float*    Wt1  = (float*)(ws + 168427520);         // 131,072 B
  float*    biasF= (float*)(ws + 168558592);         // 2,048 B
  float*    part = (float*)(ws + 168560640);         // 2,097,152 B
  float*    statF= (float*)(ws + 170657792);         // 8,192 B

  k_compose<<<dim3(1280), dim3(256), 0, stream>>>(Wal, Wbl, Wat, Wbt, Waf, Wbf, Wt);
  k_bias<<<dim3(2), dim3(256), 0, stream>>>(bal, bat, baf, bbl, bbt, bbf, Waf, Wbf, biasF);
  k_wt1<<<dim3(128), dim3(256), 0, stream>>>(Wa, Wb, Wt1);
  k1_xa<<<dim3(256, 2, 2), dim3(256), 0, stream>>>(x0, x1, Wt1, ba, bb, XA);

  for (int b = 0; b < 2; ++b) {
    const uint16_t* XAb = XA + (size_t)b * NEDGE * 128;
    k2_gather<<<dim3(1024), dim3(256), 0, stream>>>(XAb, gemm + (size_t)b * NEDGE * 4, G);
    k3_gemm<<<dim3(4, 512), dim3(256), 0, stream>>>(XAb, G, Wt, biasF, Yb);
    k3b1<<<dim3(512), dim3(256), 0, stream>>>(Yb, part);
    k3b2<<<dim3(512), dim3(128), 0, stream>>>(part, statF + b * 1024);
    k4_final<<<dim3(1024, 2), dim3(256), 0, stream>>>(
        Yb, statF + b * 1024, x0 + (size_t)b * 256 * NEDGE,
        x1 + (size_t)b * 256 * NEDGE, out + (size_t)b * 256 * NEDGE);
  }
}

// Round 3
// 450.530 us; speedup vs baseline: 1.3962x; 1.3481x over previous
//
#include <hip/hip_runtime.h>
#include <stdint.h>

// Problem constants: B=2, C=256, N=65536
#define NEDGE 65536

typedef __attribute__((ext_vector_type(4))) float f32x4;
typedef __attribute__((ext_vector_type(8))) __bf16 bf16x8;

__device__ __forceinline__ uint16_t f2bf(float f) {
  union { float f; uint32_t u; } v; v.f = f;
  uint32_t r = v.u + 0x7FFFu + ((v.u >> 16) & 1u);
  return (uint16_t)(r >> 16);
}
__device__ __forceinline__ float bflo(uint32_t u) {
  union { uint32_t u; float f; } v; v.u = u << 16; return v.f;
}
__device__ __forceinline__ float bfhi(uint32_t u) {
  union { uint32_t u; float f; } v; v.u = u & 0xFFFF0000u; return v.f;
}
__device__ __forceinline__ uint32_t packbf(float lo, float hi) {
  return (uint32_t)f2bf(lo) | ((uint32_t)f2bf(hi) << 16);
}
__device__ __forceinline__ void gload_lds16(const void* g, void* l) {
  __builtin_amdgcn_global_load_lds(
      (__attribute__((address_space(1))) uint32_t*)(uintptr_t)g,
      (__attribute__((address_space(3))) uint32_t*)l, 16, 0, 0);
}
__device__ __forceinline__ float sigm(float z) { return 1.0f / (1.0f + __expf(-z)); }

// ---------------- K0: weight composition ----------------
__global__ void k_compose(const float* __restrict__ Wal, const float* __restrict__ Wbl,
                          const float* __restrict__ Wat, const float* __restrict__ Wbt,
                          const float* __restrict__ Waf, const float* __restrict__ Wbf,
                          uint16_t* __restrict__ Wt) {
  int id = blockIdx.x * 256 + threadIdx.x;
  if (id >= 512 * 640) return;
  int j = id / 640, kk = id % 640;
  const float* Wf = (j < 256) ? Waf : Wbf;
  const float* Wl = (j < 256) ? Wal : Wbl;
  const float* Wr = (j < 256) ? Wat : Wbt;
  int jj = j & 255;
  float acc = 0.f;
  if (kk < 128) {
    int c = kk;
    for (int o = 0; o < 128; ++o) acc += Wl[o * 128 + c] * Wf[jj * 256 + o];
    for (int o = 0; o < 128; ++o) acc += Wr[(o * 128 + c) * 5 + 0] * Wf[jj * 256 + 128 + o];
  } else {
    int blkid = (kk - 128) >> 7;
    int gk = (blkid == 0) ? 1 : (blkid == 1) ? 3 : (blkid == 2) ? 2 : 4;
    int c = (kk - 128) & 127;
    for (int o = 0; o < 128; ++o) acc += Wr[(o * 128 + c) * 5 + gk] * Wf[jj * 256 + 128 + o];
  }
  Wt[j * 640 + kk] = f2bf(acc);
}

__global__ void k_bias(const float* __restrict__ bal, const float* __restrict__ bat,
                       const float* __restrict__ baf, const float* __restrict__ bbl,
                       const float* __restrict__ bbt, const float* __restrict__ bbf,
                       const float* __restrict__ Waf, const float* __restrict__ Wbf,
                       float* __restrict__ biasF) {
  int id = blockIdx.x * 256 + threadIdx.x;
  if (id >= 512) return;
  const float* Wf = (id < 256) ? Waf : Wbf;
  const float* bl = (id < 256) ? bal : bbl;
  const float* bt = (id < 256) ? bat : bbt;
  const float* bsf = (id < 256) ? baf : bbf;
  int jj = id & 255;
  float acc = bsf[jj];
  for (int o = 0; o < 128; ++o) acc += Wf[jj * 256 + o] * bl[o];
  for (int o = 0; o < 128; ++o) acc += Wf[jj * 256 + 128 + o] * bt[o];
  biasF[id] = acc;
}

// First-layer weights -> bf16, [side][j][c] row-major (B-operand layout)
__global__ void k_wt1(const float* __restrict__ Wa, const float* __restrict__ Wb,
                      uint16_t* __restrict__ W1bf) {
  int id = blockIdx.x * 256 + threadIdx.x;
  if (id >= 2 * 64 * 256) return;
  int side = id >> 14, r = id & 16383;
  W1bf[id] = f2bf(side ? Wb[r] : Wa[r]);
}

// ---------------- K1 (MFMA): XA = [Wa@x0+ba | Wb@x1+bb], (B, N, 128) bf16 ----------------
// Block: 64 n-rows x 64 j-cols (one side). 4 waves, wave wv owns rows wv*16..+15.
// A-fragments loaded directly from global x (f32, strided) with on-the-fly bf16 cvt.
// B (weights) staged once in LDS, padded row stride 264 u16 (2-way bank alias = free).
__global__ __launch_bounds__(256) void k1_xa(
    const float* __restrict__ x0, const float* __restrict__ x1,
    const uint16_t* __restrict__ W1bf, const float* __restrict__ ba,
    const float* __restrict__ bb, uint16_t* __restrict__ XA) {
  __shared__ __align__(16) uint16_t Bs[64 * 264];
  int t = threadIdx.x;
  int side = blockIdx.y, b = blockIdx.z;
  int n0 = blockIdx.x * 64;
  const float* xin = (side ? x1 : x0) + (size_t)b * 256 * NEDGE;

  // stage weights: 64 rows x 256 cols bf16 (32KB) -> Bs rows of 264
  {
    const uint16_t* src = W1bf + side * 64 * 256;
#pragma unroll
    for (int i = 0; i < 8; ++i) {
      int chunk = t * 8 + i;            // 2048 chunks of 8 u16
      int j = chunk >> 5, cp = chunk & 31;
      uint4 v = *(const uint4*)(src + j * 256 + cp * 8);
      *(uint4*)&Bs[j * 264 + cp * 8] = v;
    }
  }
  __syncthreads();

  int wv = t >> 6, l = t & 63;
  int m = l & 15, g = l >> 4;           // A-row within frag, k-group
  int nrow = n0 + wv * 16 + m;

  f32x4 acc[4];
  f32x4 zero = {0.f, 0.f, 0.f, 0.f};
#pragma unroll
  for (int cf = 0; cf < 4; ++cf) acc[cf] = zero;

#pragma unroll
  for (int ks = 0; ks < 8; ++ks) {
    const float* xp = xin + (size_t)(ks * 32 + g * 8) * NEDGE + nrow;
    float xv[8];
#pragma unroll
    for (int i = 0; i < 8; ++i) xv[i] = xp[(size_t)i * NEDGE];
    union { bf16x8 v; uint32_t u[4]; } af;
    af.u[0] = packbf(xv[0], xv[1]);
    af.u[1] = packbf(xv[2], xv[3]);
    af.u[2] = packbf(xv[4], xv[5]);
    af.u[3] = packbf(xv[6], xv[7]);
#pragma unroll
    for (int cf = 0; cf < 4; ++cf) {
      bf16x8 bfr = *(const bf16x8*)&Bs[(cf * 16 + m) * 264 + ks * 32 + g * 8];
      acc[cf] = __builtin_amdgcn_mfma_f32_16x16x32_bf16(af.v, bfr, acc[cf], 0, 0, 0);
    }
  }

  const float* bias = side ? bb : ba;
  uint16_t* XAb = XA + (size_t)b * NEDGE * 128;
#pragma unroll
  for (int cf = 0; cf < 4; ++cf) {
    float bv = bias[cf * 16 + m];
#pragma unroll
    for (int q = 0; q < 4; ++q) {
      int row = n0 + wv * 16 + g * 4 + q;
      XAb[(size_t)row * 128 + side * 64 + cf * 16 + m] = f2bf(acc[cf][q] + bv);
    }
  }
}

// ---------------- K2: gather + symmetric features -> G (N, 512) bf16 ----------------
// G cols: [0,128)=f1+f3, [128,256)=|f1-f3|, [256,384)=f2+f4, [384,512)=|f2-f4|
__device__ __forceinline__ void feat_pair(uint32_t u1, uint32_t u3, uint32_t& s, uint32_t& d) {
  float a1 = bflo(u1), b1 = bfhi(u1), a3 = bflo(u3), b3 = bfhi(u3);
  s = packbf(a1 + a3, b1 + b3);
  d = packbf(fabsf(a1 - a3), fabsf(b1 - b3));
}
__global__ void k2_gather(const uint16_t* __restrict__ XAb, const int* __restrict__ gidx,
                          uint16_t* __restrict__ G) {
  int t = threadIdx.x;
  int wid = t >> 6, lane = t & 63;
  int wbase = (blockIdx.x * 4 + wid) * 16;
  int g = lane >> 4, sl = lane & 15;
  for (int it = 0; it < 4; ++it) {
    int e0 = wbase + it * 4;
    int myidx = 0;
    if (lane < 16) myidx = gidx[(size_t)e0 * 4 + lane];
    int e = e0 + g;
    int i1 = __shfl(myidx, g * 4 + 0);
    int i2 = __shfl(myidx, g * 4 + 1);
    int i3 = __shfl(myidx, g * 4 + 2);
    int i4 = __shfl(myidx, g * 4 + 3);
    uint4 v1 = ((const uint4*)(XAb + (size_t)i1 * 128))[sl];
    uint4 v2 = ((const uint4*)(XAb + (size_t)i2 * 128))[sl];
    uint4 v3 = ((const uint4*)(XAb + (size_t)i3 * 128))[sl];
    uint4 v4 = ((const uint4*)(XAb + (size_t)i4 * 128))[sl];
    uint4 F1, F3, F2, F4;
    feat_pair(v1.x, v3.x, F1.x, F3.x); feat_pair(v1.y, v3.y, F1.y, F3.y);
    feat_pair(v1.z, v3.z, F1.z, F3.z); feat_pair(v1.w, v3.w, F1.w, F3.w);
    feat_pair(v2.x, v4.x, F2.x, F4.x); feat_pair(v2.y, v4.y, F2.y, F4.y);
    feat_pair(v2.z, v4.z, F2.z, F4.z); feat_pair(v2.w, v4.w, F2.w, F4.w);
    uint4* outr = (uint4*)(G + (size_t)e * 512);
    outr[sl] = F1; outr[16 + sl] = F3; outr[32 + sl] = F2; outr[48 + sl] = F4;
  }
}

// ---------------- K3: Y (N,512) = [XA|G](N,640) @ Wt^T + bias, bf16 out ----------------
__global__ __launch_bounds__(256, 2) void k3_gemm(
    const uint16_t* __restrict__ XAb, const uint16_t* __restrict__ G,
    const uint16_t* __restrict__ Wt, const float* __restrict__ biasF,
    uint16_t* __restrict__ Y) {
  __shared__ __align__(16) uint16_t As[128 * 64];
  __shared__ __align__(16) uint16_t Bs[128 * 64];
  int bx = blockIdx.y;   // 0..511 row tile
  int by = blockIdx.x;   // 0..3 col tile
  int t = threadIdx.x;
  int ebase = bx * 128;
  int jbase = by * 128;
  int wid = t >> 6, lane = t & 63;
  int wr = wid >> 1, wc = wid & 1;
  int m = lane & 15, half = lane >> 4;

  f32x4 acc[4][4];
  f32x4 zero = {0.f, 0.f, 0.f, 0.f};
#pragma unroll
  for (int r = 0; r < 4; ++r)
#pragma unroll
    for (int c = 0; c < 4; ++c) acc[r][c] = zero;

  for (int s = 0; s < 10; ++s) {
    const uint16_t* srcbase; size_t rstride; int koff;
    if (s < 2) { srcbase = XAb; rstride = 128; koff = s * 64; }
    else       { srcbase = G;   rstride = 512; koff = (s - 2) * 64; }
#pragma unroll
    for (int i = 0; i < 4; ++i) {
      int slot = i * 256 + t;
      int r = slot >> 3, c16 = slot & 7;
      gload_lds16(srcbase + (size_t)(ebase + r) * rstride + koff + c16 * 8, &As[slot * 8]);
    }
#pragma unroll
    for (int i = 0; i < 4; ++i) {
      int slot = i * 256 + t;
      int r = slot >> 3, c16 = slot & 7;
      gload_lds16(Wt + (size_t)(jbase + r) * 640 + s * 64 + c16 * 8, &Bs[slot * 8]);
    }
    asm volatile("s_waitcnt vmcnt(0)" ::: "memory");
    __syncthreads();
#pragma unroll
    for (int kit = 0; kit < 2; ++kit) {
      bf16x8 af[4], bf[4];
#pragma unroll
      for (int r = 0; r < 4; ++r) {
        int row = wr * 64 + r * 16 + m;
        af[r] = *(const bf16x8*)&As[row * 64 + kit * 32 + half * 8];
      }
#pragma unroll
      for (int cf = 0; cf < 4; ++cf) {
        int row = wc * 64 + cf * 16 + m;
        bf[cf] = *(const bf16x8*)&Bs[row * 64 + kit * 32 + half * 8];
      }
#pragma unroll
      for (int r = 0; r < 4; ++r)
#pragma unroll
        for (int cf = 0; cf < 4; ++cf)
          acc[r][cf] = __builtin_amdgcn_mfma_f32_16x16x32_bf16(af[r], bf[cf], acc[r][cf], 0, 0, 0);
    }
    __syncthreads();
  }
#pragma unroll
  for (int cf = 0; cf < 4; ++cf) {
    int col = jbase + wc * 64 + cf * 16 + m;
    float bv = biasF[col];
#pragma unroll
    for (int r = 0; r < 4; ++r) {
      int rowb = ebase + wr * 64 + r * 16 + half * 4;
#pragma unroll
      for (int q = 0; q < 4; ++q) {
        float v = acc[r][cf][q] + bv;
        Y[(size_t)(rowb + q) * 512 + col] = f2bf(v);
      }
    }
  }
}

// ---------------- K3b: per-column stats (deterministic two-stage) ----------------
__global__ void k3b1(const uint16_t* __restrict__ Y, float* __restrict__ part) {
  int t = threadIdx.x, ch = blockIdx.x;
  const uint32_t* Y32 = (const uint32_t*)Y;
  float s1a = 0, s2a = 0, s1b = 0, s2b = 0;
  size_t base = (size_t)ch * 128 * 256 + t;
  for (int r = 0; r < 128; ++r) {
    uint32_t v = Y32[base + (size_t)r * 256];
    float x = bflo(v), y = bfhi(v);
    s1a += x; s2a += x * x; s1b += y; s2b += y * y;
  }
  float* p = part + ((size_t)ch * 512 + 2 * t) * 2;
  p[0] = s1a; p[1] = s2a; p[2] = s1b; p[3] = s2b;
}
__global__ void k3b2(const float* __restrict__ part, float* __restrict__ statF) {
  int col = blockIdx.x, t = threadIdx.x;
  float s1 = 0, s2 = 0;
  for (int k = t; k < 512; k += 128) {
    const float* p = part + ((size_t)k * 512 + col) * 2;
    s1 += p[0]; s2 += p[1];
  }
  for (int off = 32; off; off >>= 1) { s1 += __shfl_down(s1, off); s2 += __shfl_down(s2, off); }
  __shared__ float sh[4];
  if ((t & 63) == 0) { sh[(t >> 6) * 2] = s1; sh[(t >> 6) * 2 + 1] = s2; }
  __syncthreads();
  if (t == 0) {
    s1 = sh[0] + sh[2]; s2 = sh[1] + sh[3];
    float mean = s1 * (1.0f / 65536.0f);
    float var = s2 * (1.0f / 65536.0f) - mean * mean;
    statF[col * 2] = mean;
    statF[col * 2 + 1] = rsqrtf(var + 1e-5f);
  }
}

// ---------------- K4: gate + blend, channel-major out ----------------
__global__ __launch_bounds__(256) void k4_final(
    const uint16_t* __restrict__ Y, const float* __restrict__ statF,
    const float* __restrict__ x0b, const float* __restrict__ x1b,
    float* __restrict__ outb) {
  __shared__ float W0[128][65];
  __shared__ float mA[128], rA[128], mB[128], rB[128];
  int t = threadIdx.x;
  int n0 = blockIdx.x * 64;
  int ch = blockIdx.y;
  if (t < 128) {
    mA[t] = statF[(ch * 128 + t) * 2];
    rA[t] = statF[(ch * 128 + t) * 2 + 1];
  } else {
    int q = t - 128;
    mB[q] = statF[(256 + ch * 128 + q) * 2];
    rB[q] = statF[(256 + ch * 128 + q) * 2 + 1];
  }
  __syncthreads();
  const char* Ybase = (const char*)Y;
  for (int i = t; i < 64 * 64; i += 256) {
    int row = i >> 6, cp = i & 63;
    const char* yr = Ybase + (size_t)(n0 + row) * 1024;
    uint32_t ya2 = *(const uint32_t*)(yr + ch * 256 + cp * 4);
    uint32_t yb2 = *(const uint32_t*)(yr + 512 + ch * 256 + cp * 4);
    int c0 = 2 * cp, c1 = 2 * cp + 1;
    float wa0 = sigm((bflo(ya2) - mA[c0]) * rA[c0]);
    float wa1 = sigm((bfhi(ya2) - mA[c1]) * rA[c1]);
    float wb0 = sigm((bflo(yb2) - mB[c0]) * rB[c0]);
    float wb1 = sigm((bfhi(yb2) - mB[c1]) * rB[c1]);
    W0[c0][row] = sigm(wa0 - wb0);
    W0[c1][row] = sigm(wa1 - wb1);
  }
  __syncthreads();
  int nn = t & 63, cg = t >> 6;
  for (int cc = cg; cc < 128; cc += 4) {
    int c = ch * 128 + cc;
    size_t gi = (size_t)c * NEDGE + n0 + nn;
    float w0 = W0[cc][nn];
    outb[gi] = x0b[gi] * w0 + x1b[gi] * (1.0f - w0);
  }
}

extern "C" void kernel_launch(void* const* d_in, const int* in_sizes, int n_in,
                              void* d_out, int out_size, void* d_ws, size_t ws_size,
                              hipStream_t stream) {
  const float* x0 = (const float*)d_in[0];
  const float* x1 = (const float*)d_in[1];
  const int* gemm = (const int*)d_in[2];
  const float* Wa = (const float*)d_in[3];
  const float* ba = (const float*)d_in[4];
  const float* Wb = (const float*)d_in[5];
  const float* bb = (const float*)d_in[6];
  const float* Wal = (const float*)d_in[7];
  const float* bal = (const float*)d_in[8];
  const float* Wbl = (const float*)d_in[9];
  const float* bbl = (const float*)d_in[10];
  const float* Wat = (const float*)d_in[11];
  const float* bat = (const float*)d_in[12];
  const float* Wbt = (const float*)d_in[13];
  const float* bbt = (const float*)d_in[14];
  const float* Waf = (const float*)d_in[15];
  const float* baf = (const float*)d_in[16];
  const float* Wbf = (const float*)d_in[17];
  const float* bbf = (const float*)d_in[18];
  float* out = (float*)d_out;

  char* ws = (char*)d_ws;
  uint16_t* XA   = (uint16_t*)ws;                    // 33,554,432 B
  uint16_t* G    = (uint16_t*)(ws + 33554432);       // 67,108,864 B (per-batch reuse)
  uint16_t* Yb   = (uint16_t*)(ws + 100663296);      // 67,108,864 B (per-batch reuse)
  uint16_t* Wt   = (uint16_t*)(ws + 167772160);      // 655,360 B
  uint16_t* W1bf = (uint16_t*)(ws + 168427520);      // 65,536 B
  float*    biasF= (float*)(ws + 168558592);         // 2,048 B
  float*    part = (float*)(ws + 168560640);         // 2,097,152 B
  float*    statF= (float*)(ws + 170657792);         // 8,192 B

  k_compose<<<dim3(1280), dim3(256), 0, stream>>>(Wal, Wbl, Wat, Wbt, Waf, Wbf, Wt);
  k_bias<<<dim3(2), dim3(256), 0, stream>>>(bal, bat, baf, bbl, bbt, bbf, Waf, Wbf, biasF);
  k_wt1<<<dim3(128), dim3(256), 0, stream>>>(Wa, Wb, W1bf);
  k1_xa<<<dim3(1024, 2, 2), dim3(256), 0, stream>>>(x0, x1, W1bf, ba, bb, XA);

  for (int b = 0; b < 2; ++b) {
    const uint16_t* XAb = XA + (size_t)b * NEDGE * 128;
    k2_gather<<<dim3(1024), dim3(256), 0, stream>>>(XAb, gemm + (size_t)b * NEDGE * 4, G);
    k3_gemm<<<dim3(4, 512), dim3(256), 0, stream>>>(XAb, G, Wt, biasF, Yb);
    k3b1<<<dim3(512), dim3(256), 0, stream>>>(Yb, part);
    k3b2<<<dim3(512), dim3(128), 0, stream>>>(part, statF + b * 1024);
    k4_final<<<dim3(1024, 2), dim3(256), 0, stream>>>(
        Yb, statF + b * 1024, x0 + (size_t)b * 256 * NEDGE,
        x1 + (size_t)b * 256 * NEDGE, out + (size_t)b * 256 * NEDGE);
  }
}

// Round 4
// 434.779 us; speedup vs baseline: 1.4467x; 1.0362x over previous
//
#include <hip/hip_runtime.h>
#include <stdint.h>

// Problem constants: B=2, C=256, N=65536
#define NEDGE 65536

typedef __attribute__((ext_vector_type(4))) float f32x4;
typedef __attribute__((ext_vector_type(8))) __bf16 bf16x8;

__device__ __forceinline__ uint16_t f2bf(float f) {
  union { float f; uint32_t u; } v; v.f = f;
  uint32_t r = v.u + 0x7FFFu + ((v.u >> 16) & 1u);
  return (uint16_t)(r >> 16);
}
__device__ __forceinline__ float bflo(uint32_t u) {
  union { uint32_t u; float f; } v; v.u = u << 16; return v.f;
}
__device__ __forceinline__ float bfhi(uint32_t u) {
  union { uint32_t u; float f; } v; v.u = u & 0xFFFF0000u; return v.f;
}
__device__ __forceinline__ uint32_t packbf(float lo, float hi) {
  return (uint32_t)f2bf(lo) | ((uint32_t)f2bf(hi) << 16);
}
__device__ __forceinline__ void gload_lds16(const void* g, void* l) {
  __builtin_amdgcn_global_load_lds(
      (__attribute__((address_space(1))) uint32_t*)(uintptr_t)g,
      (__attribute__((address_space(3))) uint32_t*)l, 16, 0, 0);
}
__device__ __forceinline__ float sigm(float z) { return 1.0f / (1.0f + __expf(-z)); }

// ---------------- K0: weight composition ----------------
__global__ void k_compose(const float* __restrict__ Wal, const float* __restrict__ Wbl,
                          const float* __restrict__ Wat, const float* __restrict__ Wbt,
                          const float* __restrict__ Waf, const float* __restrict__ Wbf,
                          uint16_t* __restrict__ Wt) {
  int id = blockIdx.x * 256 + threadIdx.x;
  if (id >= 512 * 640) return;
  int j = id / 640, kk = id % 640;
  const float* Wf = (j < 256) ? Waf : Wbf;
  const float* Wl = (j < 256) ? Wal : Wbl;
  const float* Wr = (j < 256) ? Wat : Wbt;
  int jj = j & 255;
  float acc = 0.f;
  if (kk < 128) {
    int c = kk;
    for (int o = 0; o < 128; ++o) acc += Wl[o * 128 + c] * Wf[jj * 256 + o];
    for (int o = 0; o < 128; ++o) acc += Wr[(o * 128 + c) * 5 + 0] * Wf[jj * 256 + 128 + o];
  } else {
    int blkid = (kk - 128) >> 7;
    int gk = (blkid == 0) ? 1 : (blkid == 1) ? 3 : (blkid == 2) ? 2 : 4;
    int c = (kk - 128) & 127;
    for (int o = 0; o < 128; ++o) acc += Wr[(o * 128 + c) * 5 + gk] * Wf[jj * 256 + 128 + o];
  }
  Wt[j * 640 + kk] = f2bf(acc);
}

__global__ void k_bias(const float* __restrict__ bal, const float* __restrict__ bat,
                       const float* __restrict__ baf, const float* __restrict__ bbl,
                       const float* __restrict__ bbt, const float* __restrict__ bbf,
                       const float* __restrict__ Waf, const float* __restrict__ Wbf,
                       float* __restrict__ biasF) {
  int id = blockIdx.x * 256 + threadIdx.x;
  if (id >= 512) return;
  const float* Wf = (id < 256) ? Waf : Wbf;
  const float* bl = (id < 256) ? bal : bbl;
  const float* bt = (id < 256) ? bat : bbt;
  const float* bsf = (id < 256) ? baf : bbf;
  int jj = id & 255;
  float acc = bsf[jj];
  for (int o = 0; o < 128; ++o) acc += Wf[jj * 256 + o] * bl[o];
  for (int o = 0; o < 128; ++o) acc += Wf[jj * 256 + 128 + o] * bt[o];
  biasF[id] = acc;
}

// First-layer weights -> bf16, [side][j][c] row-major (B-operand layout)
__global__ void k_wt1(const float* __restrict__ Wa, const float* __restrict__ Wb,
                      uint16_t* __restrict__ W1bf) {
  int id = blockIdx.x * 256 + threadIdx.x;
  if (id >= 2 * 64 * 256) return;
  int side = id >> 14, r = id & 16383;
  W1bf[id] = f2bf(side ? Wb[r] : Wa[r]);
}

// ---------------- K1 (MFMA + async LDS staging): XA = [Wa@x0+ba | Wb@x1+bb] ----------------
// Block: 128 n-rows x 64 j-cols (one side, one batch). 4 waves; wave wv owns
// n-rows {rf*64 + wv*16 + m} for rf=0,1. K-chunks of 32 channels, double-buffered.
// Xs swizzle (16B blocks): pb = lb ^ (g<<2) where g = c_local>>3 -> 2-way max on reads.
// Bs swizzle: pb = lb ^ (j&7). Both staged via global_load_lds with pre-swizzled source.
__global__ __launch_bounds__(256) void k1_xa(
    const float* __restrict__ x0, const float* __restrict__ x1,
    const uint16_t* __restrict__ W1bf, const float* __restrict__ ba,
    const float* __restrict__ bb, uint16_t* __restrict__ XA) {
  __shared__ __align__(16) float Xs[2][32 * 128];    // 2 x 16 KB
  __shared__ __align__(16) uint16_t Bs[64 * 256];    // 32 KB
  int t = threadIdx.x;
  int side = blockIdx.y, b = blockIdx.z;
  int n0 = blockIdx.x * 128;
  const float* xin = (side ? x1 : x0) + (size_t)b * 256 * NEDGE + n0;
  const uint16_t* wsrc = W1bf + side * 64 * 256;

  // stage Bs (once): 2048 slots of 16B
#pragma unroll
  for (int q = 0; q < 8; ++q) {
    int s = q * 256 + t;
    int j = s >> 5, pb = s & 31;
    int lb = pb ^ (j & 7);
    gload_lds16(wsrc + j * 256 + lb * 8, &Bs[s * 8]);
  }
  // stage x chunk 0: 1024 slots of 16B
#pragma unroll
  for (int q = 0; q < 4; ++q) {
    int s = q * 256 + t;
    int cl = s >> 5, pb = s & 31;
    int lb = pb ^ (((cl >> 3) & 3) << 2);
    gload_lds16(xin + (size_t)cl * NEDGE + lb * 4, &Xs[0][s * 4]);
  }

  int wv = t >> 6, l = t & 63;
  int m = l & 15, g = l >> 4;

  f32x4 acc[2][4];
  f32x4 zero = {0.f, 0.f, 0.f, 0.f};
#pragma unroll
  for (int rf = 0; rf < 2; ++rf)
#pragma unroll
    for (int cf = 0; cf < 4; ++cf) acc[rf][cf] = zero;

  for (int ks = 0; ks < 8; ++ks) {
    if (ks < 7) {
      const float* xc = xin + (size_t)(ks + 1) * 32 * NEDGE;
#pragma unroll
      for (int q = 0; q < 4; ++q) {
        int s = q * 256 + t;
        int cl = s >> 5, pb = s & 31;
        int lb = pb ^ (((cl >> 3) & 3) << 2);
        gload_lds16(xc + (size_t)cl * NEDGE + lb * 4, &Xs[(ks + 1) & 1][s * 4]);
      }
      asm volatile("s_waitcnt vmcnt(4)" ::: "memory");
    } else {
      asm volatile("s_waitcnt vmcnt(0)" ::: "memory");
    }
    __syncthreads();

    const float* Xb = Xs[ks & 1];
    // B-fragments (one b128 each, swizzled row)
    bf16x8 bfr[4];
#pragma unroll
    for (int cf = 0; cf < 4; ++cf) {
      int jloc = cf * 16 + m;
      int pbb = (ks * 4 + g) ^ (jloc & 7);
      bfr[cf] = *(const bf16x8*)&Bs[jloc * 256 + pbb * 8];
    }
    // A-fragments: 8 strided f32 LDS reads per rowfrag (2-way bank alias = free)
#pragma unroll
    for (int rf = 0; rf < 2; ++rf) {
      int nloc = rf * 64 + wv * 16 + m;
      int phys = (nloc >> 2) ^ (g << 2);
      const float* base = Xb + phys * 4 + (nloc & 3);
      float xv[8];
#pragma unroll
      for (int i = 0; i < 8; ++i) xv[i] = base[(g * 8 + i) * 128];
      union { bf16x8 v; __bf16 e[8]; } af;
#pragma unroll
      for (int i = 0; i < 8; ++i) af.e[i] = (__bf16)xv[i];
#pragma unroll
      for (int cf = 0; cf < 4; ++cf)
        acc[rf][cf] = __builtin_amdgcn_mfma_f32_16x16x32_bf16(af.v, bfr[cf], acc[rf][cf], 0, 0, 0);
    }
    __syncthreads();
  }

  const float* bias = side ? bb : ba;
  uint16_t* XAb = XA + ((size_t)b * NEDGE + n0) * 128 + side * 64;
#pragma unroll
  for (int rf = 0; rf < 2; ++rf)
#pragma unroll
    for (int cf = 0; cf < 4; ++cf) {
      float bv = bias[cf * 16 + m];
#pragma unroll
      for (int q = 0; q < 4; ++q) {
        int row = rf * 64 + wv * 16 + g * 4 + q;
        XAb[(size_t)row * 128 + cf * 16 + m] = f2bf(acc[rf][cf][q] + bv);
      }
    }
}

// ---------------- K2: gather + symmetric features -> G (N, 512) bf16 ----------------
// G cols: [0,128)=f1+f3, [128,256)=|f1-f3|, [256,384)=f2+f4, [384,512)=|f2-f4|
__device__ __forceinline__ void feat_pair(uint32_t u1, uint32_t u3, uint32_t& s, uint32_t& d) {
  float a1 = bflo(u1), b1 = bfhi(u1), a3 = bflo(u3), b3 = bfhi(u3);
  s = packbf(a1 + a3, b1 + b3);
  d = packbf(fabsf(a1 - a3), fabsf(b1 - b3));
}
__global__ void k2_gather(const uint16_t* __restrict__ XAb, const int* __restrict__ gidx,
                          uint16_t* __restrict__ G) {
  int t = threadIdx.x;
  int wid = t >> 6, lane = t & 63;
  int wbase = (blockIdx.x * 4 + wid) * 16;
  int g = lane >> 4, sl = lane & 15;
  for (int it = 0; it < 4; ++it) {
    int e0 = wbase + it * 4;
    int myidx = 0;
    if (lane < 16) myidx = gidx[(size_t)e0 * 4 + lane];
    int e = e0 + g;
    int i1 = __shfl(myidx, g * 4 + 0);
    int i2 = __shfl(myidx, g * 4 + 1);
    int i3 = __shfl(myidx, g * 4 + 2);
    int i4 = __shfl(myidx, g * 4 + 3);
    uint4 v1 = ((const uint4*)(XAb + (size_t)i1 * 128))[sl];
    uint4 v2 = ((const uint4*)(XAb + (size_t)i2 * 128))[sl];
    uint4 v3 = ((const uint4*)(XAb + (size_t)i3 * 128))[sl];
    uint4 v4 = ((const uint4*)(XAb + (size_t)i4 * 128))[sl];
    uint4 F1, F3, F2, F4;
    feat_pair(v1.x, v3.x, F1.x, F3.x); feat_pair(v1.y, v3.y, F1.y, F3.y);
    feat_pair(v1.z, v3.z, F1.z, F3.z); feat_pair(v1.w, v3.w, F1.w, F3.w);
    feat_pair(v2.x, v4.x, F2.x, F4.x); feat_pair(v2.y, v4.y, F2.y, F4.y);
    feat_pair(v2.z, v4.z, F2.z, F4.z); feat_pair(v2.w, v4.w, F2.w, F4.w);
    uint4* outr = (uint4*)(G + (size_t)e * 512);
    outr[sl] = F1; outr[16 + sl] = F3; outr[32 + sl] = F2; outr[48 + sl] = F4;
  }
}

// ---------------- K3: Y (N,512) = [XA|G](N,640) @ Wt^T + bias, bf16 out ----------------
__global__ __launch_bounds__(256, 2) void k3_gemm(
    const uint16_t* __restrict__ XAb, const uint16_t* __restrict__ G,
    const uint16_t* __restrict__ Wt, const float* __restrict__ biasF,
    uint16_t* __restrict__ Y) {
  __shared__ __align__(16) uint16_t As[128 * 64];
  __shared__ __align__(16) uint16_t Bs[128 * 64];
  int bx = blockIdx.y;   // 0..511 row tile
  int by = blockIdx.x;   // 0..3 col tile
  int t = threadIdx.x;
  int ebase = bx * 128;
  int jbase = by * 128;
  int wid = t >> 6, lane = t & 63;
  int wr = wid >> 1, wc = wid & 1;
  int m = lane & 15, half = lane >> 4;

  f32x4 acc[4][4];
  f32x4 zero = {0.f, 0.f, 0.f, 0.f};
#pragma unroll
  for (int r = 0; r < 4; ++r)
#pragma unroll
    for (int c = 0; c < 4; ++c) acc[r][c] = zero;

  for (int s = 0; s < 10; ++s) {
    const uint16_t* srcbase; size_t rstride; int koff;
    if (s < 2) { srcbase = XAb; rstride = 128; koff = s * 64; }
    else       { srcbase = G;   rstride = 512; koff = (s - 2) * 64; }
#pragma unroll
    for (int i = 0; i < 4; ++i) {
      int slot = i * 256 + t;
      int r = slot >> 3, c16 = slot & 7;
      gload_lds16(srcbase + (size_t)(ebase + r) * rstride + koff + c16 * 8, &As[slot * 8]);
    }
#pragma unroll
    for (int i = 0; i < 4; ++i) {
      int slot = i * 256 + t;
      int r = slot >> 3, c16 = slot & 7;
      gload_lds16(Wt + (size_t)(jbase + r) * 640 + s * 64 + c16 * 8, &Bs[slot * 8]);
    }
    asm volatile("s_waitcnt vmcnt(0)" ::: "memory");
    __syncthreads();
#pragma unroll
    for (int kit = 0; kit < 2; ++kit) {
      bf16x8 af[4], bf[4];
#pragma unroll
      for (int r = 0; r < 4; ++r) {
        int row = wr * 64 + r * 16 + m;
        af[r] = *(const bf16x8*)&As[row * 64 + kit * 32 + half * 8];
      }
#pragma unroll
      for (int cf = 0; cf < 4; ++cf) {
        int row = wc * 64 + cf * 16 + m;
        bf[cf] = *(const bf16x8*)&Bs[row * 64 + kit * 32 + half * 8];
      }
#pragma unroll
      for (int r = 0; r < 4; ++r)
#pragma unroll
        for (int cf = 0; cf < 4; ++cf)
          acc[r][cf] = __builtin_amdgcn_mfma_f32_16x16x32_bf16(af[r], bf[cf], acc[r][cf], 0, 0, 0);
    }
    __syncthreads();
  }
#pragma unroll
  for (int cf = 0; cf < 4; ++cf) {
    int col = jbase + wc * 64 + cf * 16 + m;
    float bv = biasF[col];
#pragma unroll
    for (int r = 0; r < 4; ++r) {
      int rowb = ebase + wr * 64 + r * 16 + half * 4;
#pragma unroll
      for (int q = 0; q < 4; ++q) {
        float v = acc[r][cf][q] + bv;
        Y[(size_t)(rowb + q) * 512 + col] = f2bf(v);
      }
    }
  }
}

// ---------------- K3b: per-column stats (deterministic two-stage) ----------------
__global__ void k3b1(const uint16_t* __restrict__ Y, float* __restrict__ part) {
  int t = threadIdx.x, ch = blockIdx.x;
  const uint32_t* Y32 = (const uint32_t*)Y;
  float s1a = 0, s2a = 0, s1b = 0, s2b = 0;
  size_t base = (size_t)ch * 128 * 256 + t;
  for (int r = 0; r < 128; ++r) {
    uint32_t v = Y32[base + (size_t)r * 256];
    float x = bflo(v), y = bfhi(v);
    s1a += x; s2a += x * x; s1b += y; s2b += y * y;
  }
  float* p = part + ((size_t)ch * 512 + 2 * t) * 2;
  p[0] = s1a; p[1] = s2a; p[2] = s1b; p[3] = s2b;
}
__global__ void k3b2(const float* __restrict__ part, float* __restrict__ statF) {
  int col = blockIdx.x, t = threadIdx.x;
  float s1 = 0, s2 = 0;
  for (int k = t; k < 512; k += 128) {
    const float* p = part + ((size_t)k * 512 + col) * 2;
    s1 += p[0]; s2 += p[1];
  }
  for (int off = 32; off; off >>= 1) { s1 += __shfl_down(s1, off); s2 += __shfl_down(s2, off); }
  __shared__ float sh[4];
  if ((t & 63) == 0) { sh[(t >> 6) * 2] = s1; sh[(t >> 6) * 2 + 1] = s2; }
  __syncthreads();
  if (t == 0) {
    s1 = sh[0] + sh[2]; s2 = sh[1] + sh[3];
    float mean = s1 * (1.0f / 65536.0f);
    float var = s2 * (1.0f / 65536.0f) - mean * mean;
    statF[col * 2] = mean;
    statF[col * 2 + 1] = rsqrtf(var + 1e-5f);
  }
}

// ---------------- K4: gate + blend, channel-major out ----------------
__global__ __launch_bounds__(256) void k4_final(
    const uint16_t* __restrict__ Y, const float* __restrict__ statF,
    const float* __restrict__ x0b, const float* __restrict__ x1b,
    float* __restrict__ outb) {
  __shared__ float W0[128][65];
  __shared__ float mA[128], rA[128], mB[128], rB[128];
  int t = threadIdx.x;
  int n0 = blockIdx.x * 64;
  int ch = blockIdx.y;
  if (t < 128) {
    mA[t] = statF[(ch * 128 + t) * 2];
    rA[t] = statF[(ch * 128 + t) * 2 + 1];
  } else {
    int q = t - 128;
    mB[q] = statF[(256 + ch * 128 + q) * 2];
    rB[q] = statF[(256 + ch * 128 + q) * 2 + 1];
  }
  __syncthreads();
  const char* Ybase = (const char*)Y;
  for (int i = t; i < 64 * 64; i += 256) {
    int row = i >> 6, cp = i & 63;
    const char* yr = Ybase + (size_t)(n0 + row) * 1024;
    uint32_t ya2 = *(const uint32_t*)(yr + ch * 256 + cp * 4);
    uint32_t yb2 = *(const uint32_t*)(yr + 512 + ch * 256 + cp * 4);
    int c0 = 2 * cp, c1 = 2 * cp + 1;
    float wa0 = sigm((bflo(ya2) - mA[c0]) * rA[c0]);
    float wa1 = sigm((bfhi(ya2) - mA[c1]) * rA[c1]);
    float wb0 = sigm((bflo(yb2) - mB[c0]) * rB[c0]);
    float wb1 = sigm((bfhi(yb2) - mB[c1]) * rB[c1]);
    W0[c0][row] = sigm(wa0 - wb0);
    W0[c1][row] = sigm(wa1 - wb1);
  }
  __syncthreads();
  int nn = t & 63, cg = t >> 6;
  for (int cc = cg; cc < 128; cc += 4) {
    int c = ch * 128 + cc;
    size_t gi = (size_t)c * NEDGE + n0 + nn;
    float w0 = W0[cc][nn];
    outb[gi] = x0b[gi] * w0 + x1b[gi] * (1.0f - w0);
  }
}

extern "C" void kernel_launch(void* const* d_in, const int* in_sizes, int n_in,
                              void* d_out, int out_size, void* d_ws, size_t ws_size,
                              hipStream_t stream) {
  const float* x0 = (const float*)d_in[0];
  const float* x1 = (const float*)d_in[1];
  const int* gemm = (const int*)d_in[2];
  const float* Wa = (const float*)d_in[3];
  const float* ba = (const float*)d_in[4];
  const float* Wb = (const float*)d_in[5];
  const float* bb = (const float*)d_in[6];
  const float* Wal = (const float*)d_in[7];
  const float* bal = (const float*)d_in[8];
  const float* Wbl = (const float*)d_in[9];
  const float* bbl = (const float*)d_in[10];
  const float* Wat = (const float*)d_in[11];
  const float* bat = (const float*)d_in[12];
  const float* Wbt = (const float*)d_in[13];
  const float* bbt = (const float*)d_in[14];
  const float* Waf = (const float*)d_in[15];
  const float* baf = (const float*)d_in[16];
  const float* Wbf = (const float*)d_in[17];
  const float* bbf = (const float*)d_in[18];
  float* out = (float*)d_out;

  char* ws = (char*)d_ws;
  uint16_t* XA   = (uint16_t*)ws;                    // 33,554,432 B
  uint16_t* G    = (uint16_t*)(ws + 33554432);       // 67,108,864 B (per-batch reuse)
  uint16_t* Yb   = (uint16_t*)(ws + 100663296);      // 67,108,864 B (per-batch reuse)
  uint16_t* Wt   = (uint16_t*)(ws + 167772160);      // 655,360 B
  uint16_t* W1bf = (uint16_t*)(ws + 168427520);      // 65,536 B
  float*    biasF= (float*)(ws + 168558592);         // 2,048 B
  float*    part = (float*)(ws + 168560640);         // 2,097,152 B
  float*    statF= (float*)(ws + 170657792);         // 8,192 B

  k_compose<<<dim3(1280), dim3(256), 0, stream>>>(Wal, Wbl, Wat, Wbt, Waf, Wbf, Wt);
  k_bias<<<dim3(2), dim3(256), 0, stream>>>(bal, bat, baf, bbl, bbt, bbf, Waf, Wbf, biasF);
  k_wt1<<<dim3(128), dim3(256), 0, stream>>>(Wa, Wb, W1bf);
  k1_xa<<<dim3(512, 2, 2), dim3(256), 0, stream>>>(x0, x1, W1bf, ba, bb, XA);

  for (int b = 0; b < 2; ++b) {
    const uint16_t* XAb = XA + (size_t)b * NEDGE * 128;
    k2_gather<<<dim3(1024), dim3(256), 0, stream>>>(XAb, gemm + (size_t)b * NEDGE * 4, G);
    k3_gemm<<<dim3(4, 512), dim3(256), 0, stream>>>(XAb, G, Wt, biasF, Yb);
    k3b1<<<dim3(512), dim3(256), 0, stream>>>(Yb, part);
    k3b2<<<dim3(512), dim3(128), 0, stream>>>(part, statF + b * 1024);
    k4_final<<<dim3(1024, 2), dim3(256), 0, stream>>>(
        Yb, statF + b * 1024, x0 + (size_t)b * 256 * NEDGE,
        x1 + (size_t)b * 256 * NEDGE, out + (size_t)b * 256 * NEDGE);
  }
}

// Round 5
// 428.933 us; speedup vs baseline: 1.4665x; 1.0136x over previous
//
#include <hip/hip_runtime.h>
#include <stdint.h>

// Problem constants: B=2, C=256, N=65536
#define NEDGE 65536

typedef __attribute__((ext_vector_type(4))) float f32x4;
typedef __attribute__((ext_vector_type(8))) __bf16 bf16x8;

__device__ __forceinline__ uint16_t f2bf(float f) {
  union { float f; uint32_t u; } v; v.f = f;
  uint32_t r = v.u + 0x7FFFu + ((v.u >> 16) & 1u);
  return (uint16_t)(r >> 16);
}
__device__ __forceinline__ float bflo(uint32_t u) {
  union { uint32_t u; float f; } v; v.u = u << 16; return v.f;
}
__device__ __forceinline__ float bfhi(uint32_t u) {
  union { uint32_t u; float f; } v; v.u = u & 0xFFFF0000u; return v.f;
}
__device__ __forceinline__ uint32_t packbf(float lo, float hi) {
  return (uint32_t)f2bf(lo) | ((uint32_t)f2bf(hi) << 16);
}
__device__ __forceinline__ void gload_lds16(const void* g, void* l) {
  __builtin_amdgcn_global_load_lds(
      (__attribute__((address_space(1))) uint32_t*)(uintptr_t)g,
      (__attribute__((address_space(3))) uint32_t*)l, 16, 0, 0);
}
__device__ __forceinline__ float sigm(float z) { return 1.0f / (1.0f + __expf(-z)); }

// ---------------- K0: weight composition ----------------
__global__ void k_compose(const float* __restrict__ Wal, const float* __restrict__ Wbl,
                          const float* __restrict__ Wat, const float* __restrict__ Wbt,
                          const float* __restrict__ Waf, const float* __restrict__ Wbf,
                          uint16_t* __restrict__ Wt) {
  int id = blockIdx.x * 256 + threadIdx.x;
  if (id >= 512 * 640) return;
  int j = id / 640, kk = id % 640;
  const float* Wf = (j < 256) ? Waf : Wbf;
  const float* Wl = (j < 256) ? Wal : Wbl;
  const float* Wr = (j < 256) ? Wat : Wbt;
  int jj = j & 255;
  float acc = 0.f;
  if (kk < 128) {
    int c = kk;
    for (int o = 0; o < 128; ++o) acc += Wl[o * 128 + c] * Wf[jj * 256 + o];
    for (int o = 0; o < 128; ++o) acc += Wr[(o * 128 + c) * 5 + 0] * Wf[jj * 256 + 128 + o];
  } else {
    int blkid = (kk - 128) >> 7;
    int gk = (blkid == 0) ? 1 : (blkid == 1) ? 3 : (blkid == 2) ? 2 : 4;
    int c = (kk - 128) & 127;
    for (int o = 0; o < 128; ++o) acc += Wr[(o * 128 + c) * 5 + gk] * Wf[jj * 256 + 128 + o];
  }
  Wt[j * 640 + kk] = f2bf(acc);
}

__global__ void k_bias(const float* __restrict__ bal, const float* __restrict__ bat,
                       const float* __restrict__ baf, const float* __restrict__ bbl,
                       const float* __restrict__ bbt, const float* __restrict__ bbf,
                       const float* __restrict__ Waf, const float* __restrict__ Wbf,
                       float* __restrict__ biasF) {
  int id = blockIdx.x * 256 + threadIdx.x;
  if (id >= 512) return;
  const float* Wf = (id < 256) ? Waf : Wbf;
  const float* bl = (id < 256) ? bal : bbl;
  const float* bt = (id < 256) ? bat : bbt;
  const float* bsf = (id < 256) ? baf : bbf;
  int jj = id & 255;
  float acc = bsf[jj];
  for (int o = 0; o < 128; ++o) acc += Wf[jj * 256 + o] * bl[o];
  for (int o = 0; o < 128; ++o) acc += Wf[jj * 256 + 128 + o] * bt[o];
  biasF[id] = acc;
}

// First-layer weights -> bf16, [side][j][c] row-major (B-operand layout)
__global__ void k_wt1(const float* __restrict__ Wa, const float* __restrict__ Wb,
                      uint16_t* __restrict__ W1bf) {
  int id = blockIdx.x * 256 + threadIdx.x;
  if (id >= 2 * 64 * 256) return;
  int side = id >> 14, r = id & 16383;
  W1bf[id] = f2bf(side ? Wb[r] : Wa[r]);
}

// ---------------- K1 (MFMA, counted-vmcnt raw-barrier pipeline) ----------------
// Block: 128 n-rows x 64 j-cols (one side, one batch). 4 waves.
// 3 Xs buffers (depth-2 prefetch, 16KB each) + Bs 32KB = 80KB -> 2 blocks/CU.
// vmcnt never drained to 0 in the main loop (T4); raw s_barrier (no compiler drain).
__global__ __launch_bounds__(256) void k1_xa(
    const float* __restrict__ x0, const float* __restrict__ x1,
    const uint16_t* __restrict__ W1bf, const float* __restrict__ ba,
    const float* __restrict__ bb, uint16_t* __restrict__ XA) {
  __shared__ __align__(16) float Xs[3][32 * 128];    // 3 x 16 KB
  __shared__ __align__(16) uint16_t Bs[64 * 256];    // 32 KB
  int t = threadIdx.x;
  int side = blockIdx.y, b = blockIdx.z;
  int n0 = blockIdx.x * 128;
  const float* xin = (side ? x1 : x0) + (size_t)b * 256 * NEDGE + n0;
  const uint16_t* wsrc = W1bf + side * 64 * 256;

  // stage Bs (8 instr/thread), source pre-swizzled: phys block pb holds logical pb^(j&7)
#pragma unroll
  for (int q = 0; q < 8; ++q) {
    int s = q * 256 + t;
    int j = s >> 5, pb = s & 31;
    int lb = pb ^ (j & 7);
    gload_lds16(wsrc + j * 256 + lb * 8, &Bs[s * 8]);
  }
  // stage x chunks 0,1 (4 instr each)
#pragma unroll
  for (int c = 0; c < 2; ++c) {
#pragma unroll
    for (int q = 0; q < 4; ++q) {
      int s = q * 256 + t;
      int cl = s >> 5, pb = s & 31;
      int lb = pb ^ (((cl >> 3) & 3) << 2);
      gload_lds16(xin + (size_t)(c * 32 + cl) * NEDGE + lb * 4, &Xs[c][s * 4]);
    }
  }

  int wv = t >> 6, l = t & 63;
  int m = l & 15, g = l >> 4;

  f32x4 acc[2][4];
  f32x4 zero = {0.f, 0.f, 0.f, 0.f};
#pragma unroll
  for (int rf = 0; rf < 2; ++rf)
#pragma unroll
    for (int cf = 0; cf < 4; ++cf) acc[rf][cf] = zero;

#pragma unroll
  for (int ks = 0; ks < 8; ++ks) {
    if (ks < 6) {
      const float* xc = xin + (size_t)(ks + 2) * 32 * NEDGE;
#pragma unroll
      for (int q = 0; q < 4; ++q) {
        int s = q * 256 + t;
        int cl = s >> 5, pb = s & 31;
        int lb = pb ^ (((cl >> 3) & 3) << 2);
        gload_lds16(xc + (size_t)cl * NEDGE + lb * 4, &Xs[(ks + 2) % 3][s * 4]);
      }
      asm volatile("s_waitcnt vmcnt(8)" ::: "memory");
    } else if (ks == 6) {
      asm volatile("s_waitcnt vmcnt(4)" ::: "memory");
    } else {
      asm volatile("s_waitcnt vmcnt(0)" ::: "memory");
    }
    __builtin_amdgcn_sched_barrier(0);
    __builtin_amdgcn_s_barrier();

    const float* Xb = Xs[ks % 3];
    bf16x8 bfr[4];
#pragma unroll
    for (int cf = 0; cf < 4; ++cf) {
      int jloc = cf * 16 + m;
      int pbb = (ks * 4 + g) ^ (jloc & 7);
      bfr[cf] = *(const bf16x8*)&Bs[jloc * 256 + pbb * 8];
    }
#pragma unroll
    for (int rf = 0; rf < 2; ++rf) {
      int nloc = rf * 64 + wv * 16 + m;
      int phys = (nloc >> 2) ^ (g << 2);
      const float* base = Xb + phys * 4 + (nloc & 3);
      float xv[8];
#pragma unroll
      for (int i = 0; i < 8; ++i) xv[i] = base[(g * 8 + i) * 128];
      union { bf16x8 v; __bf16 e[8]; } af;
#pragma unroll
      for (int i = 0; i < 8; ++i) af.e[i] = (__bf16)xv[i];
#pragma unroll
      for (int cf = 0; cf < 4; ++cf)
        acc[rf][cf] = __builtin_amdgcn_mfma_f32_16x16x32_bf16(af.v, bfr[cf], acc[rf][cf], 0, 0, 0);
    }
    __builtin_amdgcn_s_barrier();
  }

  const float* bias = side ? bb : ba;
  uint16_t* XAb = XA + ((size_t)b * NEDGE + n0) * 128 + side * 64;
#pragma unroll
  for (int rf = 0; rf < 2; ++rf)
#pragma unroll
    for (int cf = 0; cf < 4; ++cf) {
      float bv = bias[cf * 16 + m];
#pragma unroll
      for (int q = 0; q < 4; ++q) {
        int row = rf * 64 + wv * 16 + g * 4 + q;
        XAb[(size_t)row * 128 + cf * 16 + m] = f2bf(acc[rf][cf][q] + bv);
      }
    }
}

// ---------------- K2: gather + symmetric features -> G (N, 512) bf16 ----------------
__device__ __forceinline__ void feat_pair(uint32_t u1, uint32_t u3, uint32_t& s, uint32_t& d) {
  float a1 = bflo(u1), b1 = bfhi(u1), a3 = bflo(u3), b3 = bfhi(u3);
  s = packbf(a1 + a3, b1 + b3);
  d = packbf(fabsf(a1 - a3), fabsf(b1 - b3));
}
__global__ void k2_gather(const uint16_t* __restrict__ XAb, const int* __restrict__ gidx,
                          uint16_t* __restrict__ G) {
  int t = threadIdx.x;
  int wid = t >> 6, lane = t & 63;
  int wbase = (blockIdx.x * 4 + wid) * 16;
  int g = lane >> 4, sl = lane & 15;
  for (int it = 0; it < 4; ++it) {
    int e0 = wbase + it * 4;
    int myidx = 0;
    if (lane < 16) myidx = gidx[(size_t)e0 * 4 + lane];
    int e = e0 + g;
    int i1 = __shfl(myidx, g * 4 + 0);
    int i2 = __shfl(myidx, g * 4 + 1);
    int i3 = __shfl(myidx, g * 4 + 2);
    int i4 = __shfl(myidx, g * 4 + 3);
    uint4 v1 = ((const uint4*)(XAb + (size_t)i1 * 128))[sl];
    uint4 v2 = ((const uint4*)(XAb + (size_t)i2 * 128))[sl];
    uint4 v3 = ((const uint4*)(XAb + (size_t)i3 * 128))[sl];
    uint4 v4 = ((const uint4*)(XAb + (size_t)i4 * 128))[sl];
    uint4 F1, F3, F2, F4;
    feat_pair(v1.x, v3.x, F1.x, F3.x); feat_pair(v1.y, v3.y, F1.y, F3.y);
    feat_pair(v1.z, v3.z, F1.z, F3.z); feat_pair(v1.w, v3.w, F1.w, F3.w);
    feat_pair(v2.x, v4.x, F2.x, F4.x); feat_pair(v2.y, v4.y, F2.y, F4.y);
    feat_pair(v2.z, v4.z, F2.z, F4.z); feat_pair(v2.w, v4.w, F2.w, F4.w);
    uint4* outr = (uint4*)(G + (size_t)e * 512);
    outr[sl] = F1; outr[16 + sl] = F3; outr[32 + sl] = F2; outr[48 + sl] = F4;
  }
}

// ---------------- K3: Y (N,512) = [XA|G](N,640) @ Wt^T + bias ----------------
// Double-buffered LDS, counted vmcnt(8), raw barriers, XOR-swizzled b128 reads
// (blk ^= row&7, applied via pre-swizzled gload_lds SOURCE; dest stays linear).
__global__ __launch_bounds__(256, 2) void k3_gemm(
    const uint16_t* __restrict__ XAb, const uint16_t* __restrict__ G,
    const uint16_t* __restrict__ Wt, const float* __restrict__ biasF,
    uint16_t* __restrict__ Y) {
  __shared__ __align__(16) uint16_t As[2][128 * 64];
  __shared__ __align__(16) uint16_t Bs2[2][128 * 64];
  int bx = blockIdx.y;   // 0..511 row tile
  int by = blockIdx.x;   // 0..3 col tile
  int t = threadIdx.x;
  int ebase = bx * 128;
  int jbase = by * 128;
  int wid = t >> 6, lane = t & 63;
  int wr = wid >> 1, wc = wid & 1;
  int m = lane & 15, half = lane >> 4;

  f32x4 acc[4][4];
  f32x4 zero = {0.f, 0.f, 0.f, 0.f};
#pragma unroll
  for (int r = 0; r < 4; ++r)
#pragma unroll
    for (int c = 0; c < 4; ++c) acc[r][c] = zero;

#define K3_STAGE(s_, bi)                                                        \
  do {                                                                          \
    const uint16_t* srcb; size_t rstr; int koff;                                \
    if ((s_) < 2) { srcb = XAb; rstr = 128; koff = (s_) * 64; }                 \
    else          { srcb = G;   rstr = 512; koff = ((s_) - 2) * 64; }           \
    _Pragma("unroll")                                                           \
    for (int i = 0; i < 4; ++i) {                                               \
      int slot = i * 256 + t; int r = slot >> 3, c16 = slot & 7;                \
      gload_lds16(srcb + (size_t)(ebase + r) * rstr + koff + (c16 ^ (r & 7)) * 8, \
                  &As[bi][slot * 8]);                                           \
    }                                                                           \
    _Pragma("unroll")                                                           \
    for (int i = 0; i < 4; ++i) {                                               \
      int slot = i * 256 + t; int r = slot >> 3, c16 = slot & 7;                \
      gload_lds16(Wt + (size_t)(jbase + r) * 640 + (s_) * 64 + (c16 ^ (r & 7)) * 8, \
                  &Bs2[bi][slot * 8]);                                          \
    }                                                                           \
  } while (0)

  K3_STAGE(0, 0);

#pragma unroll
  for (int s = 0; s < 10; ++s) {
    if (s < 9) {
      K3_STAGE(s + 1, (s + 1) & 1);
      asm volatile("s_waitcnt vmcnt(8)" ::: "memory");
    } else {
      asm volatile("s_waitcnt vmcnt(0)" ::: "memory");
    }
    __builtin_amdgcn_sched_barrier(0);
    __builtin_amdgcn_s_barrier();

    const uint16_t* Ab = As[s & 1];
    const uint16_t* Bb = Bs2[s & 1];
#pragma unroll
    for (int kit = 0; kit < 2; ++kit) {
      bf16x8 af[4], bf[4];
#pragma unroll
      for (int r = 0; r < 4; ++r) {
        int row = wr * 64 + r * 16 + m;
        af[r] = *(const bf16x8*)&Ab[row * 64 + ((kit * 4 + half) ^ (m & 7)) * 8];
      }
#pragma unroll
      for (int cf = 0; cf < 4; ++cf) {
        int row = wc * 64 + cf * 16 + m;
        bf[cf] = *(const bf16x8*)&Bb[row * 64 + ((kit * 4 + half) ^ (m & 7)) * 8];
      }
#pragma unroll
      for (int r = 0; r < 4; ++r)
#pragma unroll
        for (int cf = 0; cf < 4; ++cf)
          acc[r][cf] = __builtin_amdgcn_mfma_f32_16x16x32_bf16(af[r], bf[cf], acc[r][cf], 0, 0, 0);
    }
    __builtin_amdgcn_s_barrier();
  }
#undef K3_STAGE

#pragma unroll
  for (int cf = 0; cf < 4; ++cf) {
    int col = jbase + wc * 64 + cf * 16 + m;
    float bv = biasF[col];
#pragma unroll
    for (int r = 0; r < 4; ++r) {
      int rowb = ebase + wr * 64 + r * 16 + half * 4;
#pragma unroll
      for (int q = 0; q < 4; ++q) {
        float v = acc[r][cf][q] + bv;
        Y[(size_t)(rowb + q) * 512 + col] = f2bf(v);
      }
    }
  }
}

// ---------------- K3b: per-column stats (deterministic two-stage) ----------------
__global__ void k3b1(const uint16_t* __restrict__ Y, float* __restrict__ part) {
  int t = threadIdx.x, ch = blockIdx.x;
  const uint32_t* Y32 = (const uint32_t*)Y;
  float s1a = 0, s2a = 0, s1b = 0, s2b = 0;
  size_t base = (size_t)ch * 128 * 256 + t;
  for (int r = 0; r < 128; ++r) {
    uint32_t v = Y32[base + (size_t)r * 256];
    float x = bflo(v), y = bfhi(v);
    s1a += x; s2a += x * x; s1b += y; s2b += y * y;
  }
  float* p = part + ((size_t)ch * 512 + 2 * t) * 2;
  p[0] = s1a; p[1] = s2a; p[2] = s1b; p[3] = s2b;
}
__global__ void k3b2(const float* __restrict__ part, float* __restrict__ statF) {
  int col = blockIdx.x, t = threadIdx.x;
  float s1 = 0, s2 = 0;
  for (int k = t; k < 512; k += 128) {
    const float* p = part + ((size_t)k * 512 + col) * 2;
    s1 += p[0]; s2 += p[1];
  }
  for (int off = 32; off; off >>= 1) { s1 += __shfl_down(s1, off); s2 += __shfl_down(s2, off); }
  __shared__ float sh[4];
  if ((t & 63) == 0) { sh[(t >> 6) * 2] = s1; sh[(t >> 6) * 2 + 1] = s2; }
  __syncthreads();
  if (t == 0) {
    s1 = sh[0] + sh[2]; s2 = sh[1] + sh[3];
    float mean = s1 * (1.0f / 65536.0f);
    float var = s2 * (1.0f / 65536.0f) - mean * mean;
    statF[col * 2] = mean;
    statF[col * 2 + 1] = rsqrtf(var + 1e-5f);
  }
}

// ---------------- K4: gate + blend, channel-major out ----------------
__global__ __launch_bounds__(256) void k4_final(
    const uint16_t* __restrict__ Y, const float* __restrict__ statF,
    const float* __restrict__ x0b, const float* __restrict__ x1b,
    float* __restrict__ outb) {
  __shared__ float W0[128][65];
  __shared__ float mA[128], rA[128], mB[128], rB[128];
  int t = threadIdx.x;
  int n0 = blockIdx.x * 64;
  int ch = blockIdx.y;
  if (t < 128) {
    mA[t] = statF[(ch * 128 + t) * 2];
    rA[t] = statF[(ch * 128 + t) * 2 + 1];
  } else {
    int q = t - 128;
    mB[q] = statF[(256 + ch * 128 + q) * 2];
    rB[q] = statF[(256 + ch * 128 + q) * 2 + 1];
  }
  __syncthreads();
  const char* Ybase = (const char*)Y;
  for (int i = t; i < 64 * 64; i += 256) {
    int row = i >> 6, cp = i & 63;
    const char* yr = Ybase + (size_t)(n0 + row) * 1024;
    uint32_t ya2 = *(const uint32_t*)(yr + ch * 256 + cp * 4);
    uint32_t yb2 = *(const uint32_t*)(yr + 512 + ch * 256 + cp * 4);
    int c0 = 2 * cp, c1 = 2 * cp + 1;
    float wa0 = sigm((bflo(ya2) - mA[c0]) * rA[c0]);
    float wa1 = sigm((bfhi(ya2) - mA[c1]) * rA[c1]);
    float wb0 = sigm((bflo(yb2) - mB[c0]) * rB[c0]);
    float wb1 = sigm((bfhi(yb2) - mB[c1]) * rB[c1]);
    W0[c0][row] = sigm(wa0 - wb0);
    W0[c1][row] = sigm(wa1 - wb1);
  }
  __syncthreads();
  int nn = t & 63, cg = t >> 6;
  for (int cc = cg; cc < 128; cc += 4) {
    int c = ch * 128 + cc;
    size_t gi = (size_t)c * NEDGE + n0 + nn;
    float w0 = W0[cc][nn];
    outb[gi] = x0b[gi] * w0 + x1b[gi] * (1.0f - w0);
  }
}

extern "C" void kernel_launch(void* const* d_in, const int* in_sizes, int n_in,
                              void* d_out, int out_size, void* d_ws, size_t ws_size,
                              hipStream_t stream) {
  const float* x0 = (const float*)d_in[0];
  const float* x1 = (const float*)d_in[1];
  const int* gemm = (const int*)d_in[2];
  const float* Wa = (const float*)d_in[3];
  const float* ba = (const float*)d_in[4];
  const float* Wb = (const float*)d_in[5];
  const float* bb = (const float*)d_in[6];
  const float* Wal = (const float*)d_in[7];
  const float* bal = (const float*)d_in[8];
  const float* Wbl = (const float*)d_in[9];
  const float* bbl = (const float*)d_in[10];
  const float* Wat = (const float*)d_in[11];
  const float* bat = (const float*)d_in[12];
  const float* Wbt = (const float*)d_in[13];
  const float* bbt = (const float*)d_in[14];
  const float* Waf = (const float*)d_in[15];
  const float* baf = (const float*)d_in[16];
  const float* Wbf = (const float*)d_in[17];
  const float* bbf = (const float*)d_in[18];
  float* out = (float*)d_out;

  char* ws = (char*)d_ws;
  uint16_t* XA   = (uint16_t*)ws;                    // 33,554,432 B
  uint16_t* G    = (uint16_t*)(ws + 33554432);       // 67,108,864 B (per-batch reuse)
  uint16_t* Yb   = (uint16_t*)(ws + 100663296);      // 67,108,864 B (per-batch reuse)
  uint16_t* Wt   = (uint16_t*)(ws + 167772160);      // 655,360 B
  uint16_t* W1bf = (uint16_t*)(ws + 168427520);      // 65,536 B
  float*    biasF= (float*)(ws + 168558592);         // 2,048 B
  float*    part = (float*)(ws + 168560640);         // 2,097,152 B
  float*    statF= (float*)(ws + 170657792);         // 8,192 B

  k_compose<<<dim3(1280), dim3(256), 0, stream>>>(Wal, Wbl, Wat, Wbt, Waf, Wbf, Wt);
  k_bias<<<dim3(2), dim3(256), 0, stream>>>(bal, bat, baf, bbl, bbt, bbf, Waf, Wbf, biasF);
  k_wt1<<<dim3(128), dim3(256), 0, stream>>>(Wa, Wb, W1bf);
  k1_xa<<<dim3(512, 2, 2), dim3(256), 0, stream>>>(x0, x1, W1bf, ba, bb, XA);

  for (int b = 0; b < 2; ++b) {
    const uint16_t* XAb = XA + (size_t)b * NEDGE * 128;
    k2_gather<<<dim3(1024), dim3(256), 0, stream>>>(XAb, gemm + (size_t)b * NEDGE * 4, G);
    k3_gemm<<<dim3(4, 512), dim3(256), 0, stream>>>(XAb, G, Wt, biasF, Yb);
    k3b1<<<dim3(512), dim3(256), 0, stream>>>(Yb, part);
    k3b2<<<dim3(512), dim3(128), 0, stream>>>(part, statF + b * 1024);
    k4_final<<<dim3(1024, 2), dim3(256), 0, stream>>>(
        Yb, statF + b * 1024, x0 + (size_t)b * 256 * NEDGE,
        x1 + (size_t)b * 256 * NEDGE, out + (size_t)b * 256 * NEDGE);
  }
}

// Round 6
// 425.844 us; speedup vs baseline: 1.4771x; 1.0073x over previous
//
#include <hip/hip_runtime.h>
#include <stdint.h>

// Problem constants: B=2, C=256, N=65536
#define NEDGE 65536

typedef __attribute__((ext_vector_type(4))) float f32x4;
typedef __attribute__((ext_vector_type(8))) __bf16 bf16x8;

__device__ __forceinline__ uint16_t f2bf(float f) {
  union { float f; uint32_t u; } v; v.f = f;
  uint32_t r = v.u + 0x7FFFu + ((v.u >> 16) & 1u);
  return (uint16_t)(r >> 16);
}
__device__ __forceinline__ float bflo(uint32_t u) {
  union { uint32_t u; float f; } v; v.u = u << 16; return v.f;
}
__device__ __forceinline__ float bfhi(uint32_t u) {
  union { uint32_t u; float f; } v; v.u = u & 0xFFFF0000u; return v.f;
}
__device__ __forceinline__ uint32_t packbf(float lo, float hi) {
  return (uint32_t)f2bf(lo) | ((uint32_t)f2bf(hi) << 16);
}
__device__ __forceinline__ void gload_lds16(const void* g, void* l) {
  __builtin_amdgcn_global_load_lds(
      (__attribute__((address_space(1))) uint32_t*)(uintptr_t)g,
      (__attribute__((address_space(3))) uint32_t*)l, 16, 0, 0);
}
__device__ __forceinline__ float sigm(float z) { return 1.0f / (1.0f + __expf(-z)); }

// ---------------- K0: weight composition ----------------
__global__ void k_compose(const float* __restrict__ Wal, const float* __restrict__ Wbl,
                          const float* __restrict__ Wat, const float* __restrict__ Wbt,
                          const float* __restrict__ Waf, const float* __restrict__ Wbf,
                          uint16_t* __restrict__ Wt) {
  int id = blockIdx.x * 256 + threadIdx.x;
  if (id >= 512 * 640) return;
  int j = id / 640, kk = id % 640;
  const float* Wf = (j < 256) ? Waf : Wbf;
  const float* Wl = (j < 256) ? Wal : Wbl;
  const float* Wr = (j < 256) ? Wat : Wbt;
  int jj = j & 255;
  float acc = 0.f;
  if (kk < 128) {
    int c = kk;
    for (int o = 0; o < 128; ++o) acc += Wl[o * 128 + c] * Wf[jj * 256 + o];
    for (int o = 0; o < 128; ++o) acc += Wr[(o * 128 + c) * 5 + 0] * Wf[jj * 256 + 128 + o];
  } else {
    int blkid = (kk - 128) >> 7;
    int gk = (blkid == 0) ? 1 : (blkid == 1) ? 3 : (blkid == 2) ? 2 : 4;
    int c = (kk - 128) & 127;
    for (int o = 0; o < 128; ++o) acc += Wr[(o * 128 + c) * 5 + gk] * Wf[jj * 256 + 128 + o];
  }
  Wt[j * 640 + kk] = f2bf(acc);
}

__global__ void k_bias(const float* __restrict__ bal, const float* __restrict__ bat,
                       const float* __restrict__ baf, const float* __restrict__ bbl,
                       const float* __restrict__ bbt, const float* __restrict__ bbf,
                       const float* __restrict__ Waf, const float* __restrict__ Wbf,
                       float* __restrict__ biasF) {
  int id = blockIdx.x * 256 + threadIdx.x;
  if (id >= 512) return;
  const float* Wf = (id < 256) ? Waf : Wbf;
  const float* bl = (id < 256) ? bal : bbl;
  const float* bt = (id < 256) ? bat : bbt;
  const float* bsf = (id < 256) ? baf : bbf;
  int jj = id & 255;
  float acc = bsf[jj];
  for (int o = 0; o < 128; ++o) acc += Wf[jj * 256 + o] * bl[o];
  for (int o = 0; o < 128; ++o) acc += Wf[jj * 256 + 128 + o] * bt[o];
  biasF[id] = acc;
}

// First-layer weights -> bf16, [side][j][c] row-major (B-operand layout)
__global__ void k_wt1(const float* __restrict__ Wa, const float* __restrict__ Wb,
                      uint16_t* __restrict__ W1bf) {
  int id = blockIdx.x * 256 + threadIdx.x;
  if (id >= 2 * 64 * 256) return;
  int side = id >> 14, r = id & 16383;
  W1bf[id] = f2bf(side ? Wb[r] : Wa[r]);
}

// ---------------- K1 (MFMA, reg-staged contiguous reads + bf16 transposed LDS) ----
// Block: 256 n x 64 j (one side, one batch), 4 waves. Chunk = 32 channels.
// Global: lane n4 reads dwordx4 -> each wave-instr covers 1KB contiguous.
// In-thread 4x4 transpose -> XT[n][32ch] bf16 (row 72B), slot XOR-swizzle
// c_phys = c4 ^ ((n4>>1)&7). A-frag = 2 x ds_read_b64 per rf. Two chunks of
// loads in flight in registers (compiler-counted vmcnt); one raw barrier/chunk.
__global__ __launch_bounds__(256) void k1_xa(
    const float* __restrict__ x0, const float* __restrict__ x1,
    const uint16_t* __restrict__ W1bf, const float* __restrict__ ba,
    const float* __restrict__ bb, uint16_t* __restrict__ XA) {
  __shared__ __align__(16) uint64_t XT[2][256 * 9];   // 2 x 18432 B
  __shared__ __align__(16) uint16_t Bs[64 * 256];     // 32768 B
  int t = threadIdx.x;
  int side = blockIdx.y, b = blockIdx.z;
  int n0 = blockIdx.x * 256;
  const float* xin = (side ? x1 : x0) + (size_t)b * 256 * NEDGE + n0;
  const uint16_t* wsrc = W1bf + side * 64 * 256;

  // stage Bs via gload_lds (source pre-swizzled; read uses pbb=(ks*4+g)^(j&7))
#pragma unroll
  for (int q = 0; q < 8; ++q) {
    int s = q * 256 + t;
    int j = s >> 5, pb = s & 31;
    int lb = pb ^ (j & 7);
    gload_lds16(wsrc + j * 256 + lb * 8, &Bs[s * 8]);
  }
  asm volatile("s_waitcnt vmcnt(0)" ::: "memory");

  const int c4a = t >> 6, n4 = t & 63;        // slot 0: c4a, slot 1: c4a+4
  const int keyw = (n4 >> 1) & 7;

  f32x4 rA[8], rB[8];
  auto load_set = [&](f32x4* r, int ks) {
#pragma unroll
    for (int sl = 0; sl < 2; ++sl) {
      int c4 = c4a + sl * 4;
      const float* base = xin + (size_t)(ks * 32 + c4 * 4) * NEDGE + n4 * 4;
#pragma unroll
      for (int i = 0; i < 4; ++i)
        r[sl * 4 + i] = *(const f32x4*)(base + (size_t)i * NEDGE);
    }
  };
  auto write_set = [&](int buf, f32x4* r) {
#pragma unroll
    for (int sl = 0; sl < 2; ++sl) {
      int c4 = c4a + sl * 4;
      int cp = c4 ^ keyw;
#pragma unroll
      for (int j = 0; j < 4; ++j) {
        uint32_t lo = packbf(r[sl * 4 + 0][j], r[sl * 4 + 1][j]);
        uint32_t hi = packbf(r[sl * 4 + 2][j], r[sl * 4 + 3][j]);
        XT[buf][(size_t)(n4 * 4 + j) * 9 + cp] = (uint64_t)lo | ((uint64_t)hi << 32);
      }
    }
  };

  load_set(rA, 0);
  load_set(rB, 1);

  int wv = t >> 6, l = t & 63;
  int m = l & 15, g = l >> 4;

  f32x4 acc[4][4];
  f32x4 zero = {0.f, 0.f, 0.f, 0.f};
#pragma unroll
  for (int rf = 0; rf < 4; ++rf)
#pragma unroll
    for (int cf = 0; cf < 4; ++cf) acc[rf][cf] = zero;

#pragma unroll
  for (int ks = 0; ks < 8; ++ks) {
    f32x4* cur = (ks & 1) ? rB : rA;
    write_set(ks & 1, cur);
    if (ks < 6) load_set(cur, ks + 2);
    asm volatile("s_waitcnt lgkmcnt(0)" ::: "memory");
    __builtin_amdgcn_s_barrier();
    __builtin_amdgcn_sched_barrier(0);

    bf16x8 bfr[4];
#pragma unroll
    for (int cf = 0; cf < 4; ++cf) {
      int jloc = cf * 16 + m;
      int pbb = (ks * 4 + g) ^ (jloc & 7);
      bfr[cf] = *(const bf16x8*)&Bs[jloc * 256 + pbb * 8];
    }
#pragma unroll
    for (int rf = 0; rf < 4; ++rf) {
      int n = rf * 64 + wv * 16 + m;
      int key = (n >> 3) & 7;
      union { uint64_t u[2]; bf16x8 v; } af;
      af.u[0] = XT[ks & 1][(size_t)n * 9 + ((2 * g) ^ key)];
      af.u[1] = XT[ks & 1][(size_t)n * 9 + ((2 * g + 1) ^ key)];
#pragma unroll
      for (int cf = 0; cf < 4; ++cf)
        acc[rf][cf] = __builtin_amdgcn_mfma_f32_16x16x32_bf16(af.v, bfr[cf], acc[rf][cf], 0, 0, 0);
    }
  }

  const float* bias = side ? bb : ba;
  uint16_t* XAb = XA + ((size_t)b * NEDGE + n0) * 128 + side * 64;
#pragma unroll
  for (int rf = 0; rf < 4; ++rf)
#pragma unroll
    for (int cf = 0; cf < 4; ++cf) {
      float bv = bias[cf * 16 + m];
#pragma unroll
      for (int q = 0; q < 4; ++q) {
        int row = rf * 64 + wv * 16 + g * 4 + q;
        XAb[(size_t)row * 128 + cf * 16 + m] = f2bf(acc[rf][cf][q] + bv);
      }
    }
}

// ---------------- K2: gather + symmetric features -> G (N, 512) bf16 ----------------
__device__ __forceinline__ void feat_pair(uint32_t u1, uint32_t u3, uint32_t& s, uint32_t& d) {
  float a1 = bflo(u1), b1 = bfhi(u1), a3 = bflo(u3), b3 = bfhi(u3);
  s = packbf(a1 + a3, b1 + b3);
  d = packbf(fabsf(a1 - a3), fabsf(b1 - b3));
}
__global__ void k2_gather(const uint16_t* __restrict__ XAb, const int* __restrict__ gidx,
                          uint16_t* __restrict__ G) {
  int t = threadIdx.x;
  int wid = t >> 6, lane = t & 63;
  int wbase = (blockIdx.x * 4 + wid) * 16;
  int g = lane >> 4, sl = lane & 15;
  for (int it = 0; it < 4; ++it) {
    int e0 = wbase + it * 4;
    int myidx = 0;
    if (lane < 16) myidx = gidx[(size_t)e0 * 4 + lane];
    int e = e0 + g;
    int i1 = __shfl(myidx, g * 4 + 0);
    int i2 = __shfl(myidx, g * 4 + 1);
    int i3 = __shfl(myidx, g * 4 + 2);
    int i4 = __shfl(myidx, g * 4 + 3);
    uint4 v1 = ((const uint4*)(XAb + (size_t)i1 * 128))[sl];
    uint4 v2 = ((const uint4*)(XAb + (size_t)i2 * 128))[sl];
    uint4 v3 = ((const uint4*)(XAb + (size_t)i3 * 128))[sl];
    uint4 v4 = ((const uint4*)(XAb + (size_t)i4 * 128))[sl];
    uint4 F1, F3, F2, F4;
    feat_pair(v1.x, v3.x, F1.x, F3.x); feat_pair(v1.y, v3.y, F1.y, F3.y);
    feat_pair(v1.z, v3.z, F1.z, F3.z); feat_pair(v1.w, v3.w, F1.w, F3.w);
    feat_pair(v2.x, v4.x, F2.x, F4.x); feat_pair(v2.y, v4.y, F2.y, F4.y);
    feat_pair(v2.z, v4.z, F2.z, F4.z); feat_pair(v2.w, v4.w, F2.w, F4.w);
    uint4* outr = (uint4*)(G + (size_t)e * 512);
    outr[sl] = F1; outr[16 + sl] = F3; outr[32 + sl] = F2; outr[48 + sl] = F4;
  }
}

// ---------------- K3: Y (N,512) = [XA|G](N,640) @ Wt^T + bias ----------------
__global__ __launch_bounds__(256, 2) void k3_gemm(
    const uint16_t* __restrict__ XAb, const uint16_t* __restrict__ G,
    const uint16_t* __restrict__ Wt, const float* __restrict__ biasF,
    uint16_t* __restrict__ Y) {
  __shared__ __align__(16) uint16_t As[2][128 * 64];
  __shared__ __align__(16) uint16_t Bs2[2][128 * 64];
  int bx = blockIdx.y;   // 0..511 row tile
  int by = blockIdx.x;   // 0..3 col tile
  int t = threadIdx.x;
  int ebase = bx * 128;
  int jbase = by * 128;
  int wid = t >> 6, lane = t & 63;
  int wr = wid >> 1, wc = wid & 1;
  int m = lane & 15, half = lane >> 4;

  f32x4 acc[4][4];
  f32x4 zero = {0.f, 0.f, 0.f, 0.f};
#pragma unroll
  for (int r = 0; r < 4; ++r)
#pragma unroll
    for (int c = 0; c < 4; ++c) acc[r][c] = zero;

#define K3_STAGE(s_, bi)                                                        \
  do {                                                                          \
    const uint16_t* srcb; size_t rstr; int koff;                                \
    if ((s_) < 2) { srcb = XAb; rstr = 128; koff = (s_) * 64; }                 \
    else          { srcb = G;   rstr = 512; koff = ((s_) - 2) * 64; }           \
    _Pragma("unroll")                                                           \
    for (int i = 0; i < 4; ++i) {                                               \
      int slot = i * 256 + t; int r = slot >> 3, c16 = slot & 7;                \
      gload_lds16(srcb + (size_t)(ebase + r) * rstr + koff + (c16 ^ (r & 7)) * 8, \
                  &As[bi][slot * 8]);                                           \
    }                                                                           \
    _Pragma("unroll")                                                           \
    for (int i = 0; i < 4; ++i) {                                               \
      int slot = i * 256 + t; int r = slot >> 3, c16 = slot & 7;                \
      gload_lds16(Wt + (size_t)(jbase + r) * 640 + (s_) * 64 + (c16 ^ (r & 7)) * 8, \
                  &Bs2[bi][slot * 8]);                                          \
    }                                                                           \
  } while (0)

  K3_STAGE(0, 0);

#pragma unroll
  for (int s = 0; s < 10; ++s) {
    if (s < 9) {
      K3_STAGE(s + 1, (s + 1) & 1);
      asm volatile("s_waitcnt vmcnt(8)" ::: "memory");
    } else {
      asm volatile("s_waitcnt vmcnt(0)" ::: "memory");
    }
    __builtin_amdgcn_sched_barrier(0);
    __builtin_amdgcn_s_barrier();

    const uint16_t* Ab = As[s & 1];
    const uint16_t* Bb = Bs2[s & 1];
#pragma unroll
    for (int kit = 0; kit < 2; ++kit) {
      bf16x8 af[4], bf[4];
#pragma unroll
      for (int r = 0; r < 4; ++r) {
        int row = wr * 64 + r * 16 + m;
        af[r] = *(const bf16x8*)&Ab[row * 64 + ((kit * 4 + half) ^ (m & 7)) * 8];
      }
#pragma unroll
      for (int cf = 0; cf < 4; ++cf) {
        int row = wc * 64 + cf * 16 + m;
        bf[cf] = *(const bf16x8*)&Bb[row * 64 + ((kit * 4 + half) ^ (m & 7)) * 8];
      }
#pragma unroll
      for (int r = 0; r < 4; ++r)
#pragma unroll
        for (int cf = 0; cf < 4; ++cf)
          acc[r][cf] = __builtin_amdgcn_mfma_f32_16x16x32_bf16(af[r], bf[cf], acc[r][cf], 0, 0, 0);
    }
    __builtin_amdgcn_s_barrier();
  }
#undef K3_STAGE

#pragma unroll
  for (int cf = 0; cf < 4; ++cf) {
    int col = jbase + wc * 64 + cf * 16 + m;
    float bv = biasF[col];
#pragma unroll
    for (int r = 0; r < 4; ++r) {
      int rowb = ebase + wr * 64 + r * 16 + half * 4;
#pragma unroll
      for (int q = 0; q < 4; ++q) {
        float v = acc[r][cf][q] + bv;
        Y[(size_t)(rowb + q) * 512 + col] = f2bf(v);
      }
    }
  }
}

// ---------------- K3b: per-column stats (deterministic two-stage) ----------------
__global__ void k3b1(const uint16_t* __restrict__ Y, float* __restrict__ part) {
  int t = threadIdx.x, ch = blockIdx.x;
  const uint32_t* Y32 = (const uint32_t*)Y;
  float s1a = 0, s2a = 0, s1b = 0, s2b = 0;
  size_t base = (size_t)ch * 128 * 256 + t;
  for (int r = 0; r < 128; ++r) {
    uint32_t v = Y32[base + (size_t)r * 256];
    float x = bflo(v), y = bfhi(v);
    s1a += x; s2a += x * x; s1b += y; s2b += y * y;
  }
  float* p = part + ((size_t)ch * 512 + 2 * t) * 2;
  p[0] = s1a; p[1] = s2a; p[2] = s1b; p[3] = s2b;
}
__global__ void k3b2(const float* __restrict__ part, float* __restrict__ statF) {
  int col = blockIdx.x, t = threadIdx.x;
  float s1 = 0, s2 = 0;
  for (int k = t; k < 512; k += 128) {
    const float* p = part + ((size_t)k * 512 + col) * 2;
    s1 += p[0]; s2 += p[1];
  }
  for (int off = 32; off; off >>= 1) { s1 += __shfl_down(s1, off); s2 += __shfl_down(s2, off); }
  __shared__ float sh[4];
  if ((t & 63) == 0) { sh[(t >> 6) * 2] = s1; sh[(t >> 6) * 2 + 1] = s2; }
  __syncthreads();
  if (t == 0) {
    s1 = sh[0] + sh[2]; s2 = sh[1] + sh[3];
    float mean = s1 * (1.0f / 65536.0f);
    float var = s2 * (1.0f / 65536.0f) - mean * mean;
    statF[col * 2] = mean;
    statF[col * 2 + 1] = rsqrtf(var + 1e-5f);
  }
}

// ---------------- K4: gate + blend, channel-major out ----------------
__global__ __launch_bounds__(256) void k4_final(
    const uint16_t* __restrict__ Y, const float* __restrict__ statF,
    const float* __restrict__ x0b, const float* __restrict__ x1b,
    float* __restrict__ outb) {
  __shared__ float W0[128][65];
  __shared__ float mA[128], rA[128], mB[128], rB[128];
  int t = threadIdx.x;
  int n0 = blockIdx.x * 64;
  int ch = blockIdx.y;
  if (t < 128) {
    mA[t] = statF[(ch * 128 + t) * 2];
    rA[t] = statF[(ch * 128 + t) * 2 + 1];
  } else {
    int q = t - 128;
    mB[q] = statF[(256 + ch * 128 + q) * 2];
    rB[q] = statF[(256 + ch * 128 + q) * 2 + 1];
  }
  __syncthreads();
  const char* Ybase = (const char*)Y;
  for (int i = t; i < 64 * 64; i += 256) {
    int row = i >> 6, cp = i & 63;
    const char* yr = Ybase + (size_t)(n0 + row) * 1024;
    uint32_t ya2 = *(const uint32_t*)(yr + ch * 256 + cp * 4);
    uint32_t yb2 = *(const uint32_t*)(yr + 512 + ch * 256 + cp * 4);
    int c0 = 2 * cp, c1 = 2 * cp + 1;
    float wa0 = sigm((bflo(ya2) - mA[c0]) * rA[c0]);
    float wa1 = sigm((bfhi(ya2) - mA[c1]) * rA[c1]);
    float wb0 = sigm((bflo(yb2) - mB[c0]) * rB[c0]);
    float wb1 = sigm((bfhi(yb2) - mB[c1]) * rB[c1]);
    W0[c0][row] = sigm(wa0 - wb0);
    W0[c1][row] = sigm(wa1 - wb1);
  }
  __syncthreads();
  int nn = t & 63, cg = t >> 6;
  for (int cc = cg; cc < 128; cc += 4) {
    int c = ch * 128 + cc;
    size_t gi = (size_t)c * NEDGE + n0 + nn;
    float w0 = W0[cc][nn];
    outb[gi] = x0b[gi] * w0 + x1b[gi] * (1.0f - w0);
  }
}

extern "C" void kernel_launch(void* const* d_in, const int* in_sizes, int n_in,
                              void* d_out, int out_size, void* d_ws, size_t ws_size,
                              hipStream_t stream) {
  const float* x0 = (const float*)d_in[0];
  const float* x1 = (const float*)d_in[1];
  const int* gemm = (const int*)d_in[2];
  const float* Wa = (const float*)d_in[3];
  const float* ba = (const float*)d_in[4];
  const float* Wb = (const float*)d_in[5];
  const float* bb = (const float*)d_in[6];
  const float* Wal = (const float*)d_in[7];
  const float* bal = (const float*)d_in[8];
  const float* Wbl = (const float*)d_in[9];
  const float* bbl = (const float*)d_in[10];
  const float* Wat = (const float*)d_in[11];
  const float* bat = (const float*)d_in[12];
  const float* Wbt = (const float*)d_in[13];
  const float* bbt = (const float*)d_in[14];
  const float* Waf = (const float*)d_in[15];
  const float* baf = (const float*)d_in[16];
  const float* Wbf = (const float*)d_in[17];
  const float* bbf = (const float*)d_in[18];
  float* out = (float*)d_out;

  char* ws = (char*)d_ws;
  uint16_t* XA   = (uint16_t*)ws;                    // 33,554,432 B
  uint16_t* G    = (uint16_t*)(ws + 33554432);       // 67,108,864 B (per-batch reuse)
  uint16_t* Yb   = (uint16_t*)(ws + 100663296);      // 67,108,864 B (per-batch reuse)
  uint16_t* Wt   = (uint16_t*)(ws + 167772160);      // 655,360 B
  uint16_t* W1bf = (uint16_t*)(ws + 168427520);      // 65,536 B
  float*    biasF= (float*)(ws + 168558592);         // 2,048 B
  float*    part = (float*)(ws + 168560640);         // 2,097,152 B
  float*    statF= (float*)(ws + 170657792);         // 8,192 B

  k_compose<<<dim3(1280), dim3(256), 0, stream>>>(Wal, Wbl, Wat, Wbt, Waf, Wbf, Wt);
  k_bias<<<dim3(2), dim3(256), 0, stream>>>(bal, bat, baf, bbl, bbt, bbf, Waf, Wbf, biasF);
  k_wt1<<<dim3(128), dim3(256), 0, stream>>>(Wa, Wb, W1bf);
  k1_xa<<<dim3(256, 2, 2), dim3(256), 0, stream>>>(x0, x1, W1bf, ba, bb, XA);

  for (int b = 0; b < 2; ++b) {
    const uint16_t* XAb = XA + (size_t)b * NEDGE * 128;
    k2_gather<<<dim3(1024), dim3(256), 0, stream>>>(XAb, gemm + (size_t)b * NEDGE * 4, G);
    k3_gemm<<<dim3(4, 512), dim3(256), 0, stream>>>(XAb, G, Wt, biasF, Yb);
    k3b1<<<dim3(512), dim3(256), 0, stream>>>(Yb, part);
    k3b2<<<dim3(512), dim3(128), 0, stream>>>(part, statF + b * 1024);
    k4_final<<<dim3(1024, 2), dim3(256), 0, stream>>>(
        Yb, statF + b * 1024, x0 + (size_t)b * 256 * NEDGE,
        x1 + (size_t)b * 256 * NEDGE, out + (size_t)b * 256 * NEDGE);
  }
}

// Round 7
// 412.553 us; speedup vs baseline: 1.5247x; 1.0322x over previous
//
#include <hip/hip_runtime.h>
#include <stdint.h>

// Problem constants: B=2, C=256, N=65536
#define NEDGE 65536

typedef __attribute__((ext_vector_type(4))) float f32x4;
typedef __attribute__((ext_vector_type(8))) __bf16 bf16x8;

#define VMCNT(n) asm volatile("s_waitcnt vmcnt(" #n ")" ::: "memory")
#define VMCNT_LGKM0(n) asm volatile("s_waitcnt vmcnt(" #n ") lgkmcnt(0)" ::: "memory")

__device__ __forceinline__ uint16_t f2bf(float f) {
  union { float f; uint32_t u; } v; v.f = f;
  uint32_t r = v.u + 0x7FFFu + ((v.u >> 16) & 1u);
  return (uint16_t)(r >> 16);
}
__device__ __forceinline__ float bflo(uint32_t u) {
  union { uint32_t u; float f; } v; v.u = u << 16; return v.f;
}
__device__ __forceinline__ float bfhi(uint32_t u) {
  union { uint32_t u; float f; } v; v.u = u & 0xFFFF0000u; return v.f;
}
__device__ __forceinline__ uint32_t packbf(float lo, float hi) {
  return (uint32_t)f2bf(lo) | ((uint32_t)f2bf(hi) << 16);
}
__device__ __forceinline__ void gload_lds16(const void* g, void* l) {
  __builtin_amdgcn_global_load_lds(
      (__attribute__((address_space(1))) uint32_t*)(uintptr_t)g,
      (__attribute__((address_space(3))) uint32_t*)l, 16, 0, 0);
}
__device__ __forceinline__ float sigm(float z) { return 1.0f / (1.0f + __expf(-z)); }

// ---------------- K0: weight composition ----------------
__global__ void k_compose(const float* __restrict__ Wal, const float* __restrict__ Wbl,
                          const float* __restrict__ Wat, const float* __restrict__ Wbt,
                          const float* __restrict__ Waf, const float* __restrict__ Wbf,
                          uint16_t* __restrict__ Wt) {
  int id = blockIdx.x * 256 + threadIdx.x;
  if (id >= 512 * 640) return;
  int j = id / 640, kk = id % 640;
  const float* Wf = (j < 256) ? Waf : Wbf;
  const float* Wl = (j < 256) ? Wal : Wbl;
  const float* Wr = (j < 256) ? Wat : Wbt;
  int jj = j & 255;
  float acc = 0.f;
  if (kk < 128) {
    int c = kk;
    for (int o = 0; o < 128; ++o) acc += Wl[o * 128 + c] * Wf[jj * 256 + o];
    for (int o = 0; o < 128; ++o) acc += Wr[(o * 128 + c) * 5 + 0] * Wf[jj * 256 + 128 + o];
  } else {
    int blkid = (kk - 128) >> 7;
    int gk = (blkid == 0) ? 1 : (blkid == 1) ? 3 : (blkid == 2) ? 2 : 4;
    int c = (kk - 128) & 127;
    for (int o = 0; o < 128; ++o) acc += Wr[(o * 128 + c) * 5 + gk] * Wf[jj * 256 + 128 + o];
  }
  Wt[j * 640 + kk] = f2bf(acc);
}

__global__ void k_bias(const float* __restrict__ bal, const float* __restrict__ bat,
                       const float* __restrict__ baf, const float* __restrict__ bbl,
                       const float* __restrict__ bbt, const float* __restrict__ bbf,
                       const float* __restrict__ Waf, const float* __restrict__ Wbf,
                       float* __restrict__ biasF) {
  int id = blockIdx.x * 256 + threadIdx.x;
  if (id >= 512) return;
  const float* Wf = (id < 256) ? Waf : Wbf;
  const float* bl = (id < 256) ? bal : bbl;
  const float* bt = (id < 256) ? bat : bbt;
  const float* bsf = (id < 256) ? baf : bbf;
  int jj = id & 255;
  float acc = bsf[jj];
  for (int o = 0; o < 128; ++o) acc += Wf[jj * 256 + o] * bl[o];
  for (int o = 0; o < 128; ++o) acc += Wf[jj * 256 + 128 + o] * bt[o];
  biasF[id] = acc;
}

// First-layer weights -> bf16, [side][j][c] row-major
__global__ void k_wt1(const float* __restrict__ Wa, const float* __restrict__ Wb,
                      uint16_t* __restrict__ W1bf) {
  int id = blockIdx.x * 256 + threadIdx.x;
  if (id >= 2 * 64 * 256) return;
  int side = id >> 14, r = id & 16383;
  W1bf[id] = f2bf(side ? Wb[r] : Wa[r]);
}

// ---------------- K1 (swapped-operand MFMA): XA = [Wa@x0+ba | Wb@x1+bb] ----------------
// D[j][n]: A = W (M=j), B = x (N=n). x staged via gload_lds in NATIVE [c][n] layout
// (no transpose). Epilogue: 8B stores (4 consecutive j per lane quad).
// Block: 128 n x 64 j (one side/batch), 4 waves (each 32 n). 3 Xs bufs + Bs = 80KB.
__global__ __launch_bounds__(256) void k1_xa(
    const float* __restrict__ x0, const float* __restrict__ x1,
    const uint16_t* __restrict__ W1bf, const float* __restrict__ ba,
    const float* __restrict__ bb, uint16_t* __restrict__ XA) {
  __shared__ __align__(16) float Xs[3][32 * 128];    // 3 x 16 KB
  __shared__ __align__(16) uint16_t Bs[64 * 256];    // 32 KB
  int t = threadIdx.x;
  int side = blockIdx.y, b = blockIdx.z;
  int n0 = blockIdx.x * 128;
  const float* xin = (side ? x1 : x0) + (size_t)b * 256 * NEDGE + n0;
  const uint16_t* wsrc = W1bf + side * 64 * 256;

  // stage Bs: phys 16B-block pb holds logical pb^(j&7)
#pragma unroll
  for (int q = 0; q < 8; ++q) {
    int s = q * 256 + t;
    int j = s >> 5, pb = s & 31;
    int lb = pb ^ (j & 7);
    gload_lds16(wsrc + j * 256 + lb * 8, &Bs[s * 8]);
  }
  // stage x chunks 0,1: rows c (32) x 128 n f32; block swizzle key = ((row>>3)&3)<<2
#pragma unroll
  for (int c = 0; c < 2; ++c) {
#pragma unroll
    for (int q = 0; q < 4; ++q) {
      int s = q * 256 + t;
      int cl = s >> 5, pb = s & 31;
      int lb = pb ^ (((cl >> 3) & 3) << 2);
      gload_lds16(xin + (size_t)(c * 32 + cl) * NEDGE + lb * 4, &Xs[c][s * 4]);
    }
  }

  int wv = t >> 6, l = t & 63;
  int m = l & 15, g = l >> 4;
  // per-thread constant swizzled read columns for the two n-frags
  int pcol[2];
#pragma unroll
  for (int nf = 0; nf < 2; ++nf) {
    int n = wv * 32 + nf * 16 + m;
    pcol[nf] = (((n >> 2) ^ (g << 2)) << 2) + (n & 3);
  }

  f32x4 acc[2][4];  // [nf][jf]
  f32x4 zero = {0.f, 0.f, 0.f, 0.f};
#pragma unroll
  for (int nf = 0; nf < 2; ++nf)
#pragma unroll
    for (int jf = 0; jf < 4; ++jf) acc[nf][jf] = zero;

#pragma unroll
  for (int ks = 0; ks < 8; ++ks) {
    if (ks < 6) {
      const float* xc = xin + (size_t)(ks + 2) * 32 * NEDGE;
#pragma unroll
      for (int q = 0; q < 4; ++q) {
        int s = q * 256 + t;
        int cl = s >> 5, pb = s & 31;
        int lb = pb ^ (((cl >> 3) & 3) << 2);
        gload_lds16(xc + (size_t)cl * NEDGE + lb * 4, &Xs[(ks + 2) % 3][s * 4]);
      }
      VMCNT(8);
    } else if (ks == 6) {
      VMCNT(4);
    } else {
      VMCNT(0);
    }
    __builtin_amdgcn_sched_barrier(0);
    __builtin_amdgcn_s_barrier();

    const float* Xb = Xs[ks % 3];
    // A-frags: W rows (lane&15 = j), k-block (ks*4+g)
    bf16x8 af[4];
#pragma unroll
    for (int jf = 0; jf < 4; ++jf) {
      int jloc = jf * 16 + m;
      int pbb = (ks * 4 + g) ^ (jloc & 7);
      af[jf] = *(const bf16x8*)&Bs[jloc * 256 + pbb * 8];
    }
    // B-frags: x cols (lane&15 = n), 8 c-rows g*8..+7, cvt f32->bf16
#pragma unroll
    for (int nf = 0; nf < 2; ++nf) {
      const float* base = Xb + g * 8 * 128 + pcol[nf];
      float xv[8];
#pragma unroll
      for (int i = 0; i < 8; ++i) xv[i] = base[i * 128];
      union { bf16x8 v; uint32_t u[4]; } bx;
      bx.u[0] = packbf(xv[0], xv[1]);
      bx.u[1] = packbf(xv[2], xv[3]);
      bx.u[2] = packbf(xv[4], xv[5]);
      bx.u[3] = packbf(xv[6], xv[7]);
#pragma unroll
      for (int jf = 0; jf < 4; ++jf)
        acc[nf][jf] = __builtin_amdgcn_mfma_f32_16x16x32_bf16(af[jf], bx.v, acc[nf][jf], 0, 0, 0);
    }
    __builtin_amdgcn_s_barrier();
  }

  // epilogue: D[j][n]: col(lane&15)=n, row=(g*4+q)=j within frag. 8B stores.
  const float* bias = side ? bb : ba;
  uint16_t* XAb = XA + (size_t)b * NEDGE * 128;
#pragma unroll
  for (int jf = 0; jf < 4; ++jf) {
    f32x4 bv = *(const f32x4*)(bias + jf * 16 + g * 4);
#pragma unroll
    for (int nf = 0; nf < 2; ++nf) {
      int n = n0 + wv * 32 + nf * 16 + m;
      uint2 o;
      o.x = packbf(acc[nf][jf][0] + bv[0], acc[nf][jf][1] + bv[1]);
      o.y = packbf(acc[nf][jf][2] + bv[2], acc[nf][jf][3] + bv[3]);
      *(uint2*)(XAb + (size_t)n * 128 + side * 64 + jf * 16 + g * 4) = o;
    }
  }
}

// ---------------- K23: fused gather+features+GEMM+stats ----------------
// Y[j][edge-tile] = [XA | G(XA,gemm)](640) @ Wt^T + bias; G computed on the fly.
// Block: 128 edges x 256 j (col-tile), 512 threads, 8 waves (wr 2 x wc 4).
// Swapped MFMA: D[j][edge] -> 8B Y stores. Per-col partial stats -> part.
// Pipeline: counted vmcnt, raw barriers; gathers reg-staged (T14).
__global__ __launch_bounds__(512) void k23_gemm(
    const uint16_t* __restrict__ XAb, const int* __restrict__ gidx,
    const uint16_t* __restrict__ Wt, const float* __restrict__ biasF,
    uint16_t* __restrict__ Y, float* __restrict__ part) {
  __shared__ __align__(16) uint16_t As[2][128 * 64];    // 32 KB
  __shared__ __align__(16) uint16_t Bs2[2][256 * 64];   // 64 KB
  __shared__ int gi[512];                               // 2 KB
  __shared__ float sL[2][256][2];                       // 4 KB
  int t = threadIdx.x;
  int jbase = blockIdx.x * 256;   // col tile (0 or 256)
  int bx = blockIdx.y;            // row tile 0..511
  int ebase = bx * 128;
  int wid = t >> 6, lane = t & 63;
  int wr = wid >> 2, wc = wid & 3;
  int m = lane & 15, g = lane >> 4;

  // stage gather indices (128 edges x 4)
  gi[t] = gidx[(size_t)ebase * 4 + t];
  __syncthreads();

  // hoisted per-thread gather slot geometry: slots q2=0,1 -> rows r0, r0+64
  const int r0 = t >> 3, cc = t & 7;
  int iP13[2], iQ13[2], iP24[2], iQ24[2];
#pragma unroll
  for (int q2 = 0; q2 < 2; ++q2) {
    int r = r0 + q2 * 64;
    iP13[q2] = gi[r * 4 + 0]; iQ13[q2] = gi[r * 4 + 2];
    iP24[q2] = gi[r * 4 + 1]; iQ24[q2] = gi[r * 4 + 3];
  }

  uint4 grP[2][2], grQ[2][2];  // [chunk parity][slot]

#define ISSUE_GATH(v)                                                           \
  do {                                                                          \
    const int coffv = ((v) & 1) * 64;                                           \
    const int pr = ((v) - 2) >> 2; /* 0: nbrs(0,2), 1: nbrs(1,3) */             \
    _Pragma("unroll")                                                           \
    for (int q2 = 0; q2 < 2; ++q2) {                                            \
      int ip = pr ? iP24[q2] : iP13[q2];                                        \
      int iq = pr ? iQ24[q2] : iQ13[q2];                                        \
      grP[(v) & 1][q2] = *(const uint4*)(XAb + (size_t)ip * 128 + coffv + cc * 8); \
      grQ[(v) & 1][q2] = *(const uint4*)(XAb + (size_t)iq * 128 + coffv + cc * 8); \
    }                                                                           \
  } while (0)

#define ISSUE_BS(s_)                                                            \
  do {                                                                          \
    _Pragma("unroll")                                                           \
    for (int q = 0; q < 4; ++q) {                                               \
      int slot = q * 512 + t; int r = slot >> 3, c16 = slot & 7;                \
      gload_lds16(Wt + (size_t)(jbase + r) * 640 + (s_) * 64 + (c16 ^ (r & 7)) * 8, \
                  &Bs2[(s_) & 1][slot * 8]);                                    \
    }                                                                           \
  } while (0)

#define ISSUE_AS_DIRECT(s_)                                                     \
  do {                                                                          \
    _Pragma("unroll")                                                           \
    for (int q = 0; q < 2; ++q) {                                               \
      int slot = q * 512 + t; int r = slot >> 3, c16 = slot & 7;                \
      gload_lds16(XAb + (size_t)(ebase + r) * 128 + (s_) * 64 + (c16 ^ (r & 7)) * 8, \
                  &As[(s_) & 1][slot * 8]);                                     \
    }                                                                           \
  } while (0)

  // prologue: gath(2) first (oldest), then As0,Bs0,As1,Bs1
  ISSUE_GATH(2);
  ISSUE_AS_DIRECT(0);
  ISSUE_BS(0);
  ISSUE_AS_DIRECT(1);
  ISSUE_BS(1);

  f32x4 acc[4][4];  // [edge-frag r][j-frag cf]
  f32x4 zero = {0.f, 0.f, 0.f, 0.f};
#pragma unroll
  for (int r = 0; r < 4; ++r)
#pragma unroll
    for (int c = 0; c < 4; ++c) acc[r][c] = zero;

#pragma unroll
  for (int u = 0; u < 10; ++u) {
    const int su = u + 1;  // chunk being ds_written this iter
    if (su >= 2 && su <= 9) {
      if (u == 1) { VMCNT(6); } else { VMCNT(4); }  // gather regs for su ready
      const int sum_op = (((su - 2) >> 1) & 1) == 0;
      const int bi = su & 1;
#pragma unroll
      for (int q2 = 0; q2 < 2; ++q2) {
        int r = r0 + q2 * 64;
        uint4 P = grP[bi][q2], Q = grQ[bi][q2];
        uint4 R;
        if (sum_op) {
          R.x = packbf(bflo(P.x) + bflo(Q.x), bfhi(P.x) + bfhi(Q.x));
          R.y = packbf(bflo(P.y) + bflo(Q.y), bfhi(P.y) + bfhi(Q.y));
          R.z = packbf(bflo(P.z) + bflo(Q.z), bfhi(P.z) + bfhi(Q.z));
          R.w = packbf(bflo(P.w) + bflo(Q.w), bfhi(P.w) + bfhi(Q.w));
        } else {
          R.x = packbf(fabsf(bflo(P.x) - bflo(Q.x)), fabsf(bfhi(P.x) - bfhi(Q.x)));
          R.y = packbf(fabsf(bflo(P.y) - bflo(Q.y)), fabsf(bfhi(P.y) - bfhi(Q.y)));
          R.z = packbf(fabsf(bflo(P.z) - bflo(Q.z)), fabsf(bfhi(P.z) - bfhi(Q.z)));
          R.w = packbf(fabsf(bflo(P.w) - bflo(Q.w)), fabsf(bfhi(P.w) - bfhi(Q.w)));
        }
        *(uint4*)&As[bi][(r * 8 + (cc ^ (r & 7))) * 8] = R;
      }
    }
    if (u + 2 >= 3 && u + 2 <= 9) ISSUE_GATH(u + 2);
    if (su >= 2 && su <= 9) ISSUE_BS(su);
    // main wait: chunk u's Bs (+As direct) landed; keep newest 8 in flight
    if (u == 0) { VMCNT_LGKM0(6); }
    else if (u <= 7) { VMCNT_LGKM0(8); }
    else if (u == 8) { VMCNT_LGKM0(4); }
    else { VMCNT_LGKM0(0); }
    __builtin_amdgcn_sched_barrier(0);
    __builtin_amdgcn_s_barrier();

    const uint16_t* Ab = As[u & 1];
    const uint16_t* Bb = Bs2[u & 1];
#pragma unroll
    for (int kit = 0; kit < 2; ++kit) {
      bf16x8 af[4], bf[4];
#pragma unroll
      for (int r = 0; r < 4; ++r) {
        int row = wr * 64 + r * 16 + m;
        af[r] = *(const bf16x8*)&Ab[row * 64 + ((kit * 4 + g) ^ (m & 7)) * 8];
      }
#pragma unroll
      for (int cf = 0; cf < 4; ++cf) {
        int row = wc * 64 + cf * 16 + m;
        bf[cf] = *(const bf16x8*)&Bb[row * 64 + ((kit * 4 + g) ^ (m & 7)) * 8];
      }
      // swapped: A=Wt (M=j), B=edges (N=edge) -> D[j][edge]
#pragma unroll
      for (int r = 0; r < 4; ++r)
#pragma unroll
        for (int cf = 0; cf < 4; ++cf)
          acc[r][cf] = __builtin_amdgcn_mfma_f32_16x16x32_bf16(bf[cf], af[r], acc[r][cf], 0, 0, 0);
    }
    __builtin_amdgcn_s_barrier();
  }
#undef ISSUE_GATH
#undef ISSUE_BS
#undef ISSUE_AS_DIRECT

  // epilogue: D[j][edge]: lane&15 = edge, regs = 4 consecutive j (g*4+q)
  float s1[4][4], s2[4][4];  // [cf][q]
#pragma unroll
  for (int cf = 0; cf < 4; ++cf)
#pragma unroll
    for (int q = 0; q < 4; ++q) { s1[cf][q] = 0.f; s2[cf][q] = 0.f; }

#pragma unroll
  for (int cf = 0; cf < 4; ++cf) {
    f32x4 bv = *(const f32x4*)(biasF + jbase + wc * 64 + cf * 16 + g * 4);
#pragma unroll
    for (int r = 0; r < 4; ++r) {
      int eg = ebase + wr * 64 + r * 16 + m;
      float v0 = acc[r][cf][0] + bv[0];
      float v1 = acc[r][cf][1] + bv[1];
      float v2 = acc[r][cf][2] + bv[2];
      float v3 = acc[r][cf][3] + bv[3];
      s1[cf][0] += v0; s2[cf][0] += v0 * v0;
      s1[cf][1] += v1; s2[cf][1] += v1 * v1;
      s1[cf][2] += v2; s2[cf][2] += v2 * v2;
      s1[cf][3] += v3; s2[cf][3] += v3 * v3;
      uint2 o;
      o.x = packbf(v0, v1);
      o.y = packbf(v2, v3);
      *(uint2*)(Y + (size_t)eg * 512 + jbase + wc * 64 + cf * 16 + g * 4) = o;
    }
  }
  // reduce over the 16 edge-lanes (m); partners share g
#pragma unroll
  for (int cf = 0; cf < 4; ++cf)
#pragma unroll
    for (int q = 0; q < 4; ++q) {
#pragma unroll
      for (int off = 1; off < 16; off <<= 1) {
        s1[cf][q] += __shfl_xor(s1[cf][q], off);
        s2[cf][q] += __shfl_xor(s2[cf][q], off);
      }
    }
  if (m == 0) {
#pragma unroll
    for (int cf = 0; cf < 4; ++cf)
#pragma unroll
      for (int q = 0; q < 4; ++q) {
        int jl = wc * 64 + cf * 16 + g * 4 + q;
        sL[wr][jl][0] = s1[cf][q];
        sL[wr][jl][1] = s2[cf][q];
      }
  }
  __syncthreads();
  if (t < 256) {
    float a1 = sL[0][t][0] + sL[1][t][0];
    float a2 = sL[0][t][1] + sL[1][t][1];
    float* p = part + ((size_t)bx * 512 + jbase + t) * 2;
    p[0] = a1; p[1] = a2;
  }
}

// ---------------- K3b2: finalize per-column mean/rsqrt ----------------
__global__ void k3b2(const float* __restrict__ part, float* __restrict__ statF) {
  int col = blockIdx.x, t = threadIdx.x;
  float s1 = 0, s2 = 0;
  for (int k = t; k < 512; k += 128) {
    const float* p = part + ((size_t)k * 512 + col) * 2;
    s1 += p[0]; s2 += p[1];
  }
  for (int off = 32; off; off >>= 1) { s1 += __shfl_down(s1, off); s2 += __shfl_down(s2, off); }
  __shared__ float sh[4];
  if ((t & 63) == 0) { sh[(t >> 6) * 2] = s1; sh[(t >> 6) * 2 + 1] = s2; }
  __syncthreads();
  if (t == 0) {
    s1 = sh[0] + sh[2]; s2 = sh[1] + sh[3];
    float mean = s1 * (1.0f / 65536.0f);
    float var = s2 * (1.0f / 65536.0f) - mean * mean;
    statF[col * 2] = mean;
    statF[col * 2 + 1] = rsqrtf(var + 1e-5f);
  }
}

// ---------------- K4: gate + blend, channel-major out ----------------
__global__ __launch_bounds__(256) void k4_final(
    const uint16_t* __restrict__ Y, const float* __restrict__ statF,
    const float* __restrict__ x0b, const float* __restrict__ x1b,
    float* __restrict__ outb) {
  __shared__ float W0[128][65];
  __shared__ float mA[128], rA[128], mB[128], rB[128];
  int t = threadIdx.x;
  int n0 = blockIdx.x * 64;
  int ch = blockIdx.y;
  if (t < 128) {
    mA[t] = statF[(ch * 128 + t) * 2];
    rA[t] = statF[(ch * 128 + t) * 2 + 1];
  } else {
    int q = t - 128;
    mB[q] = statF[(256 + ch * 128 + q) * 2];
    rB[q] = statF[(256 + ch * 128 + q) * 2 + 1];
  }
  __syncthreads();
  const char* Ybase = (const char*)Y;
  for (int i = t; i < 64 * 64; i += 256) {
    int row = i >> 6, cp = i & 63;
    const char* yr = Ybase + (size_t)(n0 + row) * 1024;
    uint32_t ya2 = *(const uint32_t*)(yr + ch * 256 + cp * 4);
    uint32_t yb2 = *(const uint32_t*)(yr + 512 + ch * 256 + cp * 4);
    int c0 = 2 * cp, c1 = 2 * cp + 1;
    float wa0 = sigm((bflo(ya2) - mA[c0]) * rA[c0]);
    float wa1 = sigm((bfhi(ya2) - mA[c1]) * rA[c1]);
    float wb0 = sigm((bflo(yb2) - mB[c0]) * rB[c0]);
    float wb1 = sigm((bfhi(yb2) - mB[c1]) * rB[c1]);
    W0[c0][row] = sigm(wa0 - wb0);
    W0[c1][row] = sigm(wa1 - wb1);
  }
  __syncthreads();
  int nn = t & 63, cg = t >> 6;
  for (int cc = cg; cc < 128; cc += 4) {
    int c = ch * 128 + cc;
    size_t gi = (size_t)c * NEDGE + n0 + nn;
    float w0 = W0[cc][nn];
    outb[gi] = x0b[gi] * w0 + x1b[gi] * (1.0f - w0);
  }
}

extern "C" void kernel_launch(void* const* d_in, const int* in_sizes, int n_in,
                              void* d_out, int out_size, void* d_ws, size_t ws_size,
                              hipStream_t stream) {
  const float* x0 = (const float*)d_in[0];
  const float* x1 = (const float*)d_in[1];
  const int* gemm = (const int*)d_in[2];
  const float* Wa = (const float*)d_in[3];
  const float* ba = (const float*)d_in[4];
  const float* Wb = (const float*)d_in[5];
  const float* bb = (const float*)d_in[6];
  const float* Wal = (const float*)d_in[7];
  const float* bal = (const float*)d_in[8];
  const float* Wbl = (const float*)d_in[9];
  const float* bbl = (const float*)d_in[10];
  const float* Wat = (const float*)d_in[11];
  const float* bat = (const float*)d_in[12];
  const float* Wbt = (const float*)d_in[13];
  const float* bbt = (const float*)d_in[14];
  const float* Waf = (const float*)d_in[15];
  const float* baf = (const float*)d_in[16];
  const float* Wbf = (const float*)d_in[17];
  const float* bbf = (const float*)d_in[18];
  float* out = (float*)d_out;

  char* ws = (char*)d_ws;
  uint16_t* XA   = (uint16_t*)ws;                    // 33,554,432 B
  uint16_t* Yb   = (uint16_t*)(ws + 33554432);       // 67,108,864 B (per-batch reuse)
  uint16_t* Wt   = (uint16_t*)(ws + 100663296);      // 655,360 B
  uint16_t* W1bf = (uint16_t*)(ws + 101318656);      // 65,536 B
  float*    biasF= (float*)(ws + 101384192);         // 2,048 B
  float*    part = (float*)(ws + 101386240);         // 2,097,152 B (per-batch reuse)
  float*    statF= (float*)(ws + 103483392);         // 8,192 B
  // total ~103.5 MB of d_ws

  k_compose<<<dim3(1280), dim3(256), 0, stream>>>(Wal, Wbl, Wat, Wbt, Waf, Wbf, Wt);
  k_bias<<<dim3(2), dim3(256), 0, stream>>>(bal, bat, baf, bbl, bbt, bbf, Waf, Wbf, biasF);
  k_wt1<<<dim3(128), dim3(256), 0, stream>>>(Wa, Wb, W1bf);
  k1_xa<<<dim3(512, 2, 2), dim3(256), 0, stream>>>(x0, x1, W1bf, ba, bb, XA);

  for (int b = 0; b < 2; ++b) {
    const uint16_t* XAb = XA + (size_t)b * NEDGE * 128;
    k23_gemm<<<dim3(2, 512), dim3(512), 0, stream>>>(
        XAb, gemm + (size_t)b * NEDGE * 4, Wt, biasF, Yb, part);
    k3b2<<<dim3(512), dim3(128), 0, stream>>>(part, statF + b * 1024);
    k4_final<<<dim3(1024, 2), dim3(256), 0, stream>>>(
        Yb, statF + b * 1024, x0 + (size_t)b * 256 * NEDGE,
        x1 + (size_t)b * 256 * NEDGE, out + (size_t)b * 256 * NEDGE);
  }
}